// Round 7
// baseline (10370.010 us; speedup 1.0000x reference)
//
#include <hip/hip_runtime.h>
#include <hip/hip_bf16.h>
#include <hip/hip_cooperative_groups.h>
#include <cstddef>

namespace cg = cooperative_groups;

#define B 256
#define S 128
#define H 512
#define G 2048
#define APAD 648   // 640 + 8 bf16 pad -> uniform bank spread for b128 reads

typedef __attribute__((ext_vector_type(8))) short short8;
typedef __attribute__((ext_vector_type(4))) float f32x4;

__device__ __forceinline__ float sigmoidf_(float x){ return 1.f/(1.f+expf(-x)); }

// ---------------- init: zero c and h16A, y = future_init_outcome ----------------
__global__ void init_kernel(float* __restrict__ c, unsigned* __restrict__ h16A_u,
                            float* __restrict__ y, const float* __restrict__ fio){
  int i = blockIdx.x*blockDim.x + threadIdx.x;
  if (i < B*H) c[i] = 0.f;
  if (i < B*H/2) h16A_u[i] = 0u;      // two bf16 zeros
  if (i < B) y[i] = fio[i];
}

// ---------------- e_x = relu(temporal_x @ temp_W + temp_b) -> bf16 ----------------
__global__ __launch_bounds__(128) void embed_x_kernel(const float* __restrict__ tx,
    const float* __restrict__ W, const float* __restrict__ bvec,
    __hip_bfloat16* __restrict__ ex16){
  __shared__ float xs[64];
  int bt = blockIdx.x, j = threadIdx.x;
  if (j < 64) xs[j] = tx[(size_t)bt*64 + j];
  __syncthreads();
  float a = bvec[j];
  #pragma unroll 8
  for (int k = 0; k < 64; ++k) a += xs[k]*W[k*128 + j];
  ex16[(size_t)bt*128 + j] = __float2bfloat16(fmaxf(a, 0.f));
}

// ---------------- e_d = relu(static_x @ stat_W + stat_b) (fp32) ----------------
__global__ __launch_bounds__(128) void embed_d_kernel(const float* __restrict__ sx,
    const float* __restrict__ W, const float* __restrict__ bvec, float* __restrict__ ed){
  __shared__ float xs[32];
  int b = blockIdx.x, j = threadIdx.x;
  if (j < 32) xs[j] = sx[(size_t)b*32 + j];
  __syncthreads();
  float a = bvec[j];
  #pragma unroll 8
  for (int k = 0; k < 32; ++k) a += xs[k]*W[k*128 + j];
  ed[(size_t)b*128 + j] = fmaxf(a, 0.f);
}

// ---------------- gd = ed @ W[wrow0:wrow0+128] + bias  (B x 2048, fp32) ----------------
__global__ __launch_bounds__(256) void gd_kernel(const float* __restrict__ ed,
    const float* __restrict__ W, int wrow0, const float* __restrict__ bias,
    float* __restrict__ gd){
  __shared__ float eds[128];
  int b = blockIdx.x, tid = threadIdx.x;
  if (tid < 128) eds[tid] = ed[(size_t)b*128 + tid];
  __syncthreads();
  int n = blockIdx.y*256 + tid;
  float a = bias[n];
  #pragma unroll 8
  for (int k = 0; k < 128; ++k) a += eds[k]*W[(size_t)(wrow0 + k)*G + n];
  gd[(size_t)b*G + n] = a;
}

// ---- weight transpose to bf16 n-major: dst[n][k], src(k,n)= k<rowsA ? A[k][n] : Bm[k-rowsA][n]
__global__ __launch_bounds__(256) void wtrans_kernel(
    const float* __restrict__ A, int rowsA, const float* __restrict__ Bm,
    __hip_bfloat16* __restrict__ dst, int Ktot)
{
  __shared__ float tile[64][65];
  const int k0 = blockIdx.x*64, n0 = blockIdx.y*64;
  const int tid = threadIdx.x;
  const int tn = tid & 63, tq = tid >> 6;     // tq in 0..3
  #pragma unroll
  for (int i = 0; i < 16; ++i){
    int k = k0 + tq*16 + i;
    float v = (k < rowsA) ? A[(size_t)k*G + n0 + tn] : Bm[(size_t)(k-rowsA)*G + n0 + tn];
    tile[k - k0][tn] = v;
  }
  __syncthreads();
  #pragma unroll
  for (int i = 0; i < 16; ++i){
    int n = n0 + tq*16 + i;
    dst[(size_t)n*Ktot + k0 + tn] = __float2bfloat16(tile[tn][tq*16 + i]);
  }
}

// ======== persistent encoder: all 128 steps in one cooperative launch ========
// 256 blocks (1/CU) x 256 thr. Block owns b-slab 64 x h-col slab 8 (32 gate cols).
// W slab in LDS once; c, gd, Wr256 in registers across all steps.
__global__ __launch_bounds__(256) void enc_persist(
    const __hip_bfloat16* __restrict__ ex16,   // [B][S][128]
    const __hip_bfloat16* __restrict__ W16,    // [2048][640] n-major
    const float* __restrict__ gd,              // [B][2048]
    const float* __restrict__ Wr256,           // fp32 row Wih[256][*]
    const float* __restrict__ hist,            // [B][S]
    float* __restrict__ cb,                    // final c out [B][H]
    __hip_bfloat16* hA, __hip_bfloat16* hB,    // ping-pong (hA zeroed)
    __hip_bfloat16* __restrict__ eo16)         // [B][S][H]
{
  __shared__ unsigned short Ws[32][APAD];      // 41.5 KB (cols 0..639 used)
  __shared__ unsigned short As[64][APAD];      // 83 KB
  __shared__ float gsc[4][8][66];              // 8.4 KB
  cg::grid_group grid = cg::this_grid();

  const int tid = threadIdx.x;
  const int id  = blockIdx.x;
  const int jgrp = id & 63, bgrp = id >> 6;
  const int b0 = bgrp*64, j0 = jgrp*8;
  const int l  = tid & 63;
  const int wid = tid >> 6, wm = wid & 1, wn = wid >> 1;

  // ---- preload W slab (once): row cc -> n = (cc>>3)*512 + j0 + (cc&7)
  for (int i = tid; i < 32*80; i += 256){
    int cc = i / 80, s = i % 80;
    int bn = (cc >> 3)*512 + j0 + (cc & 7);
    *(uint4*)&Ws[cc][s*8] = *(const uint4*)&W16[(size_t)bn*640 + s*8];
  }

  // ---- per-thread persistent state (2 output elems: pp = tid, tid+256)
  float creg[2] = {0.f, 0.f};
  float gdreg[2][4], wrreg[2][4];
  int bl_[2], jj_[2];
  #pragma unroll
  for (int p = 0; p < 2; ++p){
    int pp = tid + p*256;
    jj_[p] = pp & 7; bl_[p] = pp >> 3;
    int b_ = b0 + bl_[p], j_ = j0 + jj_[p];
    #pragma unroll
    for (int g = 0; g < 4; ++g){
      gdreg[p][g] = gd[(size_t)b_*G + g*512 + j_];
      wrreg[p][g] = Wr256[g*512 + j_];
    }
  }
  __syncthreads();

  const __hip_bfloat16* hin = hA;
  __hip_bfloat16* hout = hB;

  const int row = tid >> 2;          // staging row 0..63
  const int sq  = tid & 3;           // staging slot phase

  for (int t = 0; t < S; ++t){
    // ---- stage A tile [64][640]: k<128 from ex16(t), k>=128 from hin
    {
      const size_t exrow = ((size_t)(b0+row)*S + t)*128;
      const size_t hrow  = (size_t)(b0+row)*H;
      uint4 tmp[10];
      #pragma unroll
      for (int i = 0; i < 10; ++i){
        const int s = sq + i*4;
        tmp[i] = (i < 4) ? *(const uint4*)&ex16[exrow + s*8]
                         : *(const uint4*)&hin[hrow + s*8 - 128];
      }
      #pragma unroll
      for (int i = 0; i < 10; ++i) *(uint4*)&As[row][(sq + i*4)*8] = tmp[i];
      #pragma unroll
      for (int i = 0; i < 10; ++i){
        const int s = sq + (i+10)*4;
        tmp[i] = *(const uint4*)&hin[hrow + s*8 - 128];
      }
      #pragma unroll
      for (int i = 0; i < 10; ++i) *(uint4*)&As[row][(sq + (i+10)*4)*8] = tmp[i];
    }
    __syncthreads();

    // ---- MFMA: 64b x 32 gate-cols, K=640
    f32x4 acc0 = {0.f,0.f,0.f,0.f}, acc1 = {0.f,0.f,0.f,0.f};
    #pragma unroll
    for (int ch = 0; ch < 20; ++ch){
      const int ko = ch*32 + (l>>4)*8;
      short8 af0 = *(const short8*)&As[wm*32 +      (l&15)][ko];
      short8 af1 = *(const short8*)&As[wm*32 + 16 + (l&15)][ko];
      short8 bfr = *(const short8*)&Ws[wn*16 +      (l&15)][ko];
      acc0 = __builtin_amdgcn_mfma_f32_16x16x32_bf16(af0, bfr, acc0, 0,0,0);
      acc1 = __builtin_amdgcn_mfma_f32_16x16x32_bf16(af1, bfr, acc1, 0,0,0);
    }
    __syncthreads();   // As reads done before gsc write (gsc separate, but keep order tight)

    // ---- gate exchange through LDS
    {
      const int jj = l & 7;
      const int g  = wn*2 + ((l>>3)&1);
      #pragma unroll
      for (int r = 0; r < 4; ++r){
        gsc[g][jj][wm*32 +      (l>>4)*4 + r] = acc0[r];
        gsc[g][jj][wm*32 + 16 + (l>>4)*4 + r] = acc1[r];
      }
    }
    __syncthreads();

    // ---- epilogue: gates -> c (regs), h (global bf16), eo16
    #pragma unroll
    for (int p = 0; p < 2; ++p){
      const int b_ = b0 + bl_[p], j_ = j0 + jj_[p];
      const float hv = hist[(size_t)b_*S + t];
      float gi = gsc[0][jj_[p]][bl_[p]] + gdreg[p][0] + hv*wrreg[p][0];
      float gf = gsc[1][jj_[p]][bl_[p]] + gdreg[p][1] + hv*wrreg[p][1];
      float gg = gsc[2][jj_[p]][bl_[p]] + gdreg[p][2] + hv*wrreg[p][2];
      float go = gsc[3][jj_[p]][bl_[p]] + gdreg[p][3] + hv*wrreg[p][3];
      float cn = sigmoidf_(gf)*creg[p] + sigmoidf_(gi)*tanhf(gg);
      float hn = sigmoidf_(go)*tanhf(cn);
      creg[p] = cn;
      __hip_bfloat16 hb = __float2bfloat16(hn);
      hout[(size_t)b_*H + j_] = hb;
      eo16[((size_t)b_*S + t)*H + j_] = hb;
    }

    __threadfence();   // release h writes (wbl2) before grid barrier
    grid.sync();
    __threadfence();   // acquire (inv) so next-step h loads are fresh

    const __hip_bfloat16* tswap = hin; hin = hout; hout = (__hip_bfloat16*)tswap;
  }

  // ---- write final c for the decoder
  #pragma unroll
  for (int p = 0; p < 2; ++p)
    cb[(size_t)(b0 + bl_[p])*H + j0 + jj_[p]] = creg[p];
}

// ======== fallback per-step encoder (round-6 kernel, kept verbatim) ========
__global__ __launch_bounds__(256) void enc_step3(
    const __hip_bfloat16* __restrict__ ex16, const __hip_bfloat16* __restrict__ hin,
    const __hip_bfloat16* __restrict__ W16, const float* __restrict__ gd,
    const float* __restrict__ Wr256, const float* __restrict__ hist,
    float* __restrict__ c, __hip_bfloat16* __restrict__ hout16,
    __hip_bfloat16* __restrict__ eo16, int t)
{
  __shared__ unsigned short As[2][4][64][8];
  __shared__ unsigned short Bs[2][4][32][8];
  __shared__ float gsc[4][8][66];
  const int tid = threadIdx.x;
  const int id  = blockIdx.x;
  const int xcd = id & 7, sub = id >> 3;
  const int jgrp = xcd*8 + (sub & 7);
  const int bgrp = sub >> 3;
  const int b0 = bgrp*64, j0 = jgrp*8;
  const int l  = tid & 63;
  const int wid = tid >> 6, wm = wid & 1, wn = wid >> 1;
  const int sb = tid & 63, skg = tid >> 6;
  const int cc = tid & 31, bkg = (tid >> 5) & 3;
  const int bn = (cc >> 3)*512 + j0 + (cc & 7);

  f32x4 acc0 = {0.f,0.f,0.f,0.f}, acc1 = {0.f,0.f,0.f,0.f};
  const size_t exrow = ((size_t)(b0+sb)*S + t)*128;
  const size_t hrow  = (size_t)(b0+sb)*H;
  const size_t wrow  = (size_t)bn*640;

  uint4 aReg, bReg;
  aReg = *(const uint4*)&ex16[exrow + skg*8];
  if (tid < 128) bReg = *(const uint4*)&W16[wrow + bkg*8];
  *(uint4*)&As[0][skg][sb][0] = aReg;
  if (tid < 128) *(uint4*)&Bs[0][bkg][cc][0] = bReg;
  __syncthreads();

  const int NC = 20;
  for (int ch = 0; ch < NC; ++ch){
    const int cur = ch & 1, nxt = cur ^ 1;
    const bool more = (ch+1 < NC);
    if (more){
      const int k = (ch+1)*32 + skg*8;
      aReg = (k < 128) ? *(const uint4*)&ex16[exrow + k]
                       : *(const uint4*)&hin[hrow + (k-128)];
      if (tid < 128) bReg = *(const uint4*)&W16[wrow + (ch+1)*32 + bkg*8];
    }
    short8 af0 = *(const short8*)&As[cur][l>>4][wm*32 + (l&15)][0];
    short8 af1 = *(const short8*)&As[cur][l>>4][wm*32 + 16 + (l&15)][0];
    short8 bfr = *(const short8*)&Bs[cur][l>>4][wn*16 + (l&15)][0];
    acc0 = __builtin_amdgcn_mfma_f32_16x16x32_bf16(af0, bfr, acc0, 0,0,0);
    acc1 = __builtin_amdgcn_mfma_f32_16x16x32_bf16(af1, bfr, acc1, 0,0,0);
    if (more){
      *(uint4*)&As[nxt][skg][sb][0] = aReg;
      if (tid < 128) *(uint4*)&Bs[nxt][bkg][cc][0] = bReg;
    }
    __syncthreads();
  }
  {
    const int jj = l & 7;
    const int g  = wn*2 + ((l>>3)&1);
    #pragma unroll
    for (int r = 0; r < 4; ++r){
      gsc[g][jj][wm*32 +      (l>>4)*4 + r] = acc0[r];
      gsc[g][jj][wm*32 + 16 + (l>>4)*4 + r] = acc1[r];
    }
  }
  __syncthreads();
  #pragma unroll
  for (int p = 0; p < 2; ++p){
    const int pp = tid + p*256;
    const int jj = pp & 7, bl = pp >> 3;
    const int b_ = b0 + bl, j_ = j0 + jj;
    const float hv = hist[(size_t)b_*S + t];
    const float* gdr = &gd[(size_t)b_*G];
    float gi = gsc[0][jj][bl] + gdr[       j_] + hv*Wr256[       j_];
    float gf = gsc[1][jj][bl] + gdr[ 512 + j_] + hv*Wr256[ 512 + j_];
    float gg = gsc[2][jj][bl] + gdr[1024 + j_] + hv*Wr256[1024 + j_];
    float go = gsc[3][jj][bl] + gdr[1536 + j_] + hv*Wr256[1536 + j_];
    const size_t ci = (size_t)b_*H + j_;
    float cn = sigmoidf_(gf)*c[ci] + sigmoidf_(gi)*tanhf(gg);
    float hn = sigmoidf_(go)*tanhf(cn);
    c[ci] = cn;
    hout16[ci] = __float2bfloat16(hn);
    eo16[((size_t)b_*S + t)*H + j_] = __float2bfloat16(hn);
  }
}

// ======== decoder step: bf16 MFMA. g = h@W16D + gdd + y*Wy + a*Wa ========
__global__ __launch_bounds__(256) void dec_step3(
    const __hip_bfloat16* __restrict__ hin, const __hip_bfloat16* __restrict__ W16,
    const float* __restrict__ gdd, const float* __restrict__ Wy,
    const float* __restrict__ Wa, const float* __restrict__ y,
    const float* __restrict__ fut, float* __restrict__ c,
    float* __restrict__ hout32, __hip_bfloat16* __restrict__ hout16, int t)
{
  __shared__ unsigned short As[2][4][64][8];
  __shared__ unsigned short Bs[2][4][32][8];
  __shared__ float gsc[4][8][66];
  const int tid = threadIdx.x;
  const int id  = blockIdx.x;
  const int xcd = id & 7, sub = id >> 3;
  const int jgrp = xcd*8 + (sub & 7);
  const int bgrp = sub >> 3;
  const int b0 = bgrp*64, j0 = jgrp*8;
  const int l  = tid & 63;
  const int wid = tid >> 6, wm = wid & 1, wn = wid >> 1;
  const int sb = tid & 63, skg = tid >> 6;
  const int cc = tid & 31, bkg = (tid >> 5) & 3;
  const int bn = (cc >> 3)*512 + j0 + (cc & 7);

  f32x4 acc0 = {0.f,0.f,0.f,0.f}, acc1 = {0.f,0.f,0.f,0.f};
  const size_t hrow = (size_t)(b0+sb)*H;
  const size_t wrow = (size_t)bn*512;

  uint4 aReg, bReg;
  aReg = *(const uint4*)&hin[hrow + skg*8];
  if (tid < 128) bReg = *(const uint4*)&W16[wrow + bkg*8];
  *(uint4*)&As[0][skg][sb][0] = aReg;
  if (tid < 128) *(uint4*)&Bs[0][bkg][cc][0] = bReg;
  __syncthreads();

  const int NC = 16;
  for (int ch = 0; ch < NC; ++ch){
    const int cur = ch & 1, nxt = cur ^ 1;
    const bool more = (ch+1 < NC);
    if (more){
      const int k = (ch+1)*32 + skg*8;
      aReg = *(const uint4*)&hin[hrow + k];
      if (tid < 128) bReg = *(const uint4*)&W16[wrow + (ch+1)*32 + bkg*8];
    }
    short8 af0 = *(const short8*)&As[cur][l>>4][wm*32 + (l&15)][0];
    short8 af1 = *(const short8*)&As[cur][l>>4][wm*32 + 16 + (l&15)][0];
    short8 bfr = *(const short8*)&Bs[cur][l>>4][wn*16 + (l&15)][0];
    acc0 = __builtin_amdgcn_mfma_f32_16x16x32_bf16(af0, bfr, acc0, 0,0,0);
    acc1 = __builtin_amdgcn_mfma_f32_16x16x32_bf16(af1, bfr, acc1, 0,0,0);
    if (more){
      *(uint4*)&As[nxt][skg][sb][0] = aReg;
      if (tid < 128) *(uint4*)&Bs[nxt][bkg][cc][0] = bReg;
    }
    __syncthreads();
  }
  {
    const int jj = l & 7;
    const int g  = wn*2 + ((l>>3)&1);
    #pragma unroll
    for (int r = 0; r < 4; ++r){
      gsc[g][jj][wm*32 +      (l>>4)*4 + r] = acc0[r];
      gsc[g][jj][wm*32 + 16 + (l>>4)*4 + r] = acc1[r];
    }
  }
  __syncthreads();
  #pragma unroll
  for (int p = 0; p < 2; ++p){
    const int pp = tid + p*256;
    const int jj = pp & 7, bl = pp >> 3;
    const int b_ = b0 + bl, j_ = j0 + jj;
    const float yv = y[b_];
    const float av = fut[(size_t)b_*16 + t];
    const float* gdr = &gdd[(size_t)b_*G];
    float gi = gsc[0][jj][bl] + gdr[       j_] + yv*Wy[       j_] + av*Wa[       j_];
    float gf = gsc[1][jj][bl] + gdr[ 512 + j_] + yv*Wy[ 512 + j_] + av*Wa[ 512 + j_];
    float gg = gsc[2][jj][bl] + gdr[1024 + j_] + yv*Wy[1024 + j_] + av*Wa[1024 + j_];
    float go = gsc[3][jj][bl] + gdr[1536 + j_] + yv*Wy[1536 + j_] + av*Wa[1536 + j_];
    const size_t ci = (size_t)b_*H + j_;
    float cn = sigmoidf_(gf)*c[ci] + sigmoidf_(gi)*tanhf(gg);
    float hn = sigmoidf_(go)*tanhf(cn);
    c[ci] = cn;
    hout32[ci] = hn;
    hout16[ci] = __float2bfloat16(hn);
  }
}

// ---------------- propensity logits + enc_We (one pass over eo16) ----------------
__global__ __launch_bounds__(256) void prop_we_kernel(
    const __hip_bfloat16* __restrict__ eo, const float* __restrict__ propW,
    const float* __restrict__ propb, const float* __restrict__ attnW,
    float* __restrict__ prop_out, float* __restrict__ encWe)
{
  int row = blockIdx.x*4 + (threadIdx.x >> 6);
  int lane = threadIdx.x & 63;
  const __hip_bfloat16* e = &eo[(size_t)row*H];
  float ap = 0.f, aw = 0.f;
  #pragma unroll
  for (int i = 0; i < 8; ++i){
    float v = __bfloat162float(e[lane + i*64]);
    ap += v*propW[lane + i*64];
    aw += v*attnW[512 + lane + i*64];
  }
  #pragma unroll
  for (int off = 32; off; off >>= 1){ ap += __shfl_down(ap, off); aw += __shfl_down(aw, off); }
  if (lane == 0){
    prop_out[row] = ap + propb[0];
    encWe[row] = aw;
  }
}

// ---------------- attention + context + prediction (per decoder step) ----------------
__global__ __launch_bounds__(256) void attn_pred_kernel(
    const __hip_bfloat16* __restrict__ eo, const float* __restrict__ encWe,
    const float* __restrict__ h,
    const float* __restrict__ attnW, const float* __restrict__ attnb,
    const float* __restrict__ outW, const float* __restrict__ outb,
    const float* __restrict__ fut,
    float* __restrict__ y, float* __restrict__ out, int t)
{
  int b = blockIdx.x, tid = threadIdx.x;
  __shared__ float hWi[512];
  __shared__ float red[256];
  __shared__ float sc[128];
  __shared__ float smax, ssum, shWh;

  float hv0 = h[(size_t)b*H + tid];
  float hv1 = h[(size_t)b*H + 256 + tid];
  hWi[tid]       = hv0 * attnW[1024 + tid];
  hWi[tid + 256] = hv1 * attnW[1024 + 256 + tid];
  red[tid] = hv0*attnW[tid] + hv1*attnW[256 + tid];
  __syncthreads();
  for (int off = 128; off; off >>= 1){
    if (tid < off) red[tid] += red[tid + off];
    __syncthreads();
  }
  if (tid == 0) shWh = red[0];
  __syncthreads();

  int lane = tid & 63;
  for (int s = (tid >> 6); s < S; s += 4){
    const __hip_bfloat16* e = &eo[((size_t)b*S + s)*H];
    float a = 0.f;
    #pragma unroll
    for (int i = 0; i < 8; ++i) a += __bfloat162float(e[lane + i*64])*hWi[lane + i*64];
    #pragma unroll
    for (int off = 32; off; off >>= 1) a += __shfl_down(a, off);
    if (lane == 0) sc[s] = tanhf(shWh + encWe[(size_t)b*S + s] + a + attnb[0]);
  }
  __syncthreads();

  if (tid < 64){
    float m = fmaxf(sc[tid], sc[tid + 64]);
    #pragma unroll
    for (int off = 32; off; off >>= 1) m = fmaxf(m, __shfl_down(m, off));
    if (tid == 0) smax = m;
  }
  __syncthreads();
  if (tid < 128){ float e = expf(sc[tid] - smax); sc[tid] = e; red[tid] = e; }
  else red[tid] = 0.f;
  __syncthreads();
  for (int off = 128; off; off >>= 1){
    if (tid < off) red[tid] += red[tid + off];
    __syncthreads();
  }
  if (tid == 0) ssum = red[0];
  __syncthreads();
  float inv = 1.f / ssum;

  float c0 = 0.f, c1 = 0.f;
  for (int s = 0; s < S; ++s){
    float w = sc[s];
    const __hip_bfloat16* e = &eo[((size_t)b*S + s)*H];
    c0 += w*__bfloat162float(e[tid]);
    c1 += w*__bfloat162float(e[tid + 256]);
  }
  c0 *= inv; c1 *= inv;

  red[tid] = hv0*outW[tid] + hv1*outW[256 + tid] + c0*outW[512 + tid] + c1*outW[768 + tid];
  __syncthreads();
  for (int off = 128; off; off >>= 1){
    if (tid < off) red[tid] += red[tid + off];
    __syncthreads();
  }
  if (tid == 0){
    float at = fut[(size_t)b*16 + t];
    float p = red[0] + at*outW[1024] + outb[0];
    y[b] = p;
    out[(size_t)b*16 + t] = p;
  }
}

extern "C" void kernel_launch(void* const* d_in, const int* in_sizes, int n_in,
                              void* d_out, int out_size, void* d_ws, size_t ws_size,
                              hipStream_t stream)
{
  const float* temporal_x = (const float*)d_in[0];
  const float* static_x   = (const float*)d_in[1];
  const float* hist       = (const float*)d_in[2];
  const float* fut        = (const float*)d_in[3];
  const float* fio        = (const float*)d_in[4];
  const float* temp_W = (const float*)d_in[5];
  const float* temp_b = (const float*)d_in[6];
  const float* stat_W = (const float*)d_in[7];
  const float* stat_b = (const float*)d_in[8];
  const float* eWih = (const float*)d_in[9];
  const float* eWhh = (const float*)d_in[10];
  const float* eb   = (const float*)d_in[11];
  const float* attnW = (const float*)d_in[12];
  const float* attnb = (const float*)d_in[13];
  const float* dWih = (const float*)d_in[14];
  const float* dWhh = (const float*)d_in[15];
  const float* dbias = (const float*)d_in[16];
  const float* outW = (const float*)d_in[17];
  const float* outb = (const float*)d_in[18];
  const float* propW = (const float*)d_in[19];
  const float* propb = (const float*)d_in[20];
  float* out = (float*)d_out;   // fp32: [B*16 preds][B*S propensity]

  // ---- workspace layout: fp32 section then bf16 section (~52.7 MB) ----
  float* ws = (float*)d_ws;
  float* ed    = ws;                           // B*128
  float* gd_e  = ed    + (size_t)B*128;        // B*G
  float* gd_d  = gd_e  + (size_t)B*G;          // B*G
  float* cb    = gd_d  + (size_t)B*G;          // B*H
  float* encWe = cb    + (size_t)B*H;          // B*S
  float* yb    = encWe + (size_t)B*S;          // B
  float* dh32  = yb    + B;                    // B*H
  __hip_bfloat16* bf = (__hip_bfloat16*)(dh32 + (size_t)B*H);
  __hip_bfloat16* ex16 = bf;                              // B*S*128
  __hip_bfloat16* eo16 = ex16 + (size_t)B*S*128;          // B*S*H
  __hip_bfloat16* h16A = eo16 + (size_t)B*S*H;            // B*H
  __hip_bfloat16* h16B = h16A + (size_t)B*H;              // B*H
  __hip_bfloat16* W16E = h16B + (size_t)B*H;              // 2048*640
  __hip_bfloat16* W16D = W16E + (size_t)G*640;            // 2048*512

  init_kernel<<<(B*H + 255)/256, 256, 0, stream>>>(cb, (unsigned*)h16A, yb, fio);
  embed_x_kernel<<<B*S, 128, 0, stream>>>(temporal_x, temp_W, temp_b, ex16);
  embed_d_kernel<<<B, 128, 0, stream>>>(static_x, stat_W, stat_b, ed);
  gd_kernel<<<dim3(B,8), 256, 0, stream>>>(ed, eWih, 128, eb, gd_e);
  gd_kernel<<<dim3(B,8), 256, 0, stream>>>(ed, dWih, 0, dbias, gd_d);
  wtrans_kernel<<<dim3(10,32), 256, 0, stream>>>(eWih, 128, eWhh, W16E, 640);
  wtrans_kernel<<<dim3(8,32),  256, 0, stream>>>(dWhh, 0,   dWhh, W16D, 512);

  // ---- persistent cooperative encoder (h_n lands in h16A; c written to cb) ----
  {
    const float* wr256p = eWih + (size_t)256*G;
    const __hip_bfloat16* ex16c = ex16;
    const __hip_bfloat16* W16Ec = W16E;
    const float* gd_ec = gd_e;
    const float* histc = hist;
    __hip_bfloat16* hAp = h16A;
    __hip_bfloat16* hBp = h16B;
    __hip_bfloat16* eo16p = eo16;
    float* cbp = cb;
    void* args[] = {(void*)&ex16c, (void*)&W16Ec, (void*)&gd_ec, (void*)&wr256p,
                    (void*)&histc, (void*)&cbp, (void*)&hAp, (void*)&hBp, (void*)&eo16p};
    hipError_t cerr = hipLaunchCooperativeKernel((const void*)enc_persist,
                                                 dim3(256), dim3(256), args, 0, stream);
    if (cerr != hipSuccess){
      // fallback: per-step launches (round-6 path)
      for (int t = 0; t < S; ++t){
        const __hip_bfloat16* hin = (t & 1) ? h16B : h16A;
        __hip_bfloat16* hout      = (t & 1) ? h16A : h16B;
        enc_step3<<<256, 256, 0, stream>>>(ex16, hin, W16E, gd_e, wr256p,
                                           hist, cb, hout, eo16, t);
      }
    }
  }

  prop_we_kernel<<<(B*S)/4, 256, 0, stream>>>(eo16, propW, propb, attnW, out + B*16, encWe);

  // decoder: t reads (t&1 ? h16B : h16A) — t=0 reads h16A (h_n), writes other.
  for (int t = 0; t < 16; ++t){
    const __hip_bfloat16* hin = (t & 1) ? h16B : h16A;
    __hip_bfloat16* hout      = (t & 1) ? h16A : h16B;
    dec_step3<<<256, 256, 0, stream>>>(hin, W16D, gd_d,
                                       dWih + (size_t)128*G, dWih + (size_t)129*G,
                                       yb, fut, cb, dh32, hout, t);
    attn_pred_kernel<<<B, 256, 0, stream>>>(eo16, encWe, dh32, attnW, attnb, outW, outb,
                                            fut, yb, out, t);
  }
}

// Round 8
// 2156.999 us; speedup vs baseline: 4.8076x; 4.8076x over previous
//
#include <hip/hip_runtime.h>
#include <hip/hip_bf16.h>
#include <cstddef>

#define B 256
#define S 128
#define H 512
#define G 2048

typedef __attribute__((ext_vector_type(8))) short short8;
typedef __attribute__((ext_vector_type(4))) float f32x4;

__device__ __forceinline__ float sigmoidf_(float x){ return 1.f/(1.f+expf(-x)); }
__device__ __forceinline__ float bflo_(unsigned u){ return __uint_as_float((u & 0xffffu) << 16); }
__device__ __forceinline__ float bfhi_(unsigned u){ return __uint_as_float(u & 0xffff0000u); }

// ---------------- init: zero c and h16A, y = future_init_outcome ----------------
__global__ void init_kernel(float* __restrict__ c, unsigned* __restrict__ h16A_u,
                            float* __restrict__ y, const float* __restrict__ fio){
  int i = blockIdx.x*blockDim.x + threadIdx.x;
  if (i < B*H) c[i] = 0.f;
  if (i < B*H/2) h16A_u[i] = 0u;      // two bf16 zeros
  if (i < B) y[i] = fio[i];
}

// ---------------- e_x = relu(temporal_x @ temp_W + temp_b) -> bf16 ----------------
__global__ __launch_bounds__(128) void embed_x_kernel(const float* __restrict__ tx,
    const float* __restrict__ W, const float* __restrict__ bvec,
    __hip_bfloat16* __restrict__ ex16){
  __shared__ float xs[64];
  int bt = blockIdx.x, j = threadIdx.x;
  if (j < 64) xs[j] = tx[(size_t)bt*64 + j];
  __syncthreads();
  float a = bvec[j];
  #pragma unroll 8
  for (int k = 0; k < 64; ++k) a += xs[k]*W[k*128 + j];
  ex16[(size_t)bt*128 + j] = __float2bfloat16(fmaxf(a, 0.f));
}

// ---------------- e_d = relu(static_x @ stat_W + stat_b) (fp32) ----------------
__global__ __launch_bounds__(128) void embed_d_kernel(const float* __restrict__ sx,
    const float* __restrict__ W, const float* __restrict__ bvec, float* __restrict__ ed){
  __shared__ float xs[32];
  int b = blockIdx.x, j = threadIdx.x;
  if (j < 32) xs[j] = sx[(size_t)b*32 + j];
  __syncthreads();
  float a = bvec[j];
  #pragma unroll 8
  for (int k = 0; k < 32; ++k) a += xs[k]*W[k*128 + j];
  ed[(size_t)b*128 + j] = fmaxf(a, 0.f);
}

// ---------------- gd = ed @ W[wrow0:wrow0+128] + bias  (B x 2048, fp32) ----------------
__global__ __launch_bounds__(256) void gd_kernel(const float* __restrict__ ed,
    const float* __restrict__ W, int wrow0, const float* __restrict__ bias,
    float* __restrict__ gd){
  __shared__ float eds[128];
  int b = blockIdx.x, tid = threadIdx.x;
  if (tid < 128) eds[tid] = ed[(size_t)b*128 + tid];
  __syncthreads();
  int n = blockIdx.y*256 + tid;
  float a = bias[n];
  #pragma unroll 8
  for (int k = 0; k < 128; ++k) a += eds[k]*W[(size_t)(wrow0 + k)*G + n];
  gd[(size_t)b*G + n] = a;
}

// ---- weight transpose to bf16 n-major: dst[n][k], src(k,n)= k<rowsA ? A[k][n] : Bm[k-rowsA][n]
__global__ __launch_bounds__(256) void wtrans_kernel(
    const float* __restrict__ A, int rowsA, const float* __restrict__ Bm,
    __hip_bfloat16* __restrict__ dst, int Ktot)
{
  __shared__ float tile[64][65];
  const int k0 = blockIdx.x*64, n0 = blockIdx.y*64;
  const int tid = threadIdx.x;
  const int tn = tid & 63, tq = tid >> 6;     // tq in 0..3
  #pragma unroll
  for (int i = 0; i < 16; ++i){
    int k = k0 + tq*16 + i;
    float v = (k < rowsA) ? A[(size_t)k*G + n0 + tn] : Bm[(size_t)(k-rowsA)*G + n0 + tn];
    tile[k - k0][tn] = v;
  }
  __syncthreads();
  #pragma unroll
  for (int i = 0; i < 16; ++i){
    int n = n0 + tq*16 + i;
    dst[(size_t)n*Ktot + k0 + tn] = __float2bfloat16(tile[tn][tq*16 + i]);
  }
}

// ======== encoder step v4: direct global->VGPR MFMA, no k-loop barriers ========
// 256 blocks (XCD-swizzled), 4 waves. Block tile: 64 b x 32 gate-cols.
__global__ __launch_bounds__(256) void enc_step4(
    const __hip_bfloat16* __restrict__ ex16,   // [B][S][128]
    const __hip_bfloat16* __restrict__ hin,    // [B][512]
    const __hip_bfloat16* __restrict__ W16,    // [2048][640] n-major
    const float* __restrict__ gd,              // [B][2048]
    const float* __restrict__ Wr256,           // fp32 row Wih[256][*]
    const float* __restrict__ hist,            // [B][S]
    float* __restrict__ c,
    __hip_bfloat16* __restrict__ hout16,
    __hip_bfloat16* __restrict__ eo16, int t)
{
  __shared__ float gsc[4][8][66];
  const int tid = threadIdx.x;
  const int id  = blockIdx.x;
  const int xcd = id & 7, sub = id >> 3;
  const int jgrp = xcd*8 + (sub & 7);          // 0..63
  const int bgrp = sub >> 3;                   // 0..3
  const int b0 = bgrp*64, j0 = jgrp*8;
  const int l  = tid & 63;
  const int wid = tid >> 6, wm = wid & 1, wn = wid >> 1;
  const int lr = l & 15, lkp = (l >> 4)*8;

  const int rowA0 = b0 + wm*32 + lr;
  const int rowA1 = rowA0 + 16;
  const int cc = wn*16 + lr;                   // 0..31
  const int bn = (cc >> 3)*512 + j0 + (cc & 7);

  const __hip_bfloat16* ep0 = &ex16[((size_t)rowA0*S + t)*128 + lkp];
  const __hip_bfloat16* ep1 = &ex16[((size_t)rowA1*S + t)*128 + lkp];
  const __hip_bfloat16* hp0 = &hin[(size_t)rowA0*H + lkp];
  const __hip_bfloat16* hp1 = &hin[(size_t)rowA1*H + lkp];
  const __hip_bfloat16* wp  = &W16[(size_t)bn*640 + lkp];

  f32x4 acc0 = {0.f,0.f,0.f,0.f}, acc1 = {0.f,0.f,0.f,0.f};
  #pragma unroll
  for (int ch = 0; ch < 4; ++ch){              // k in [0,128): ex part
    short8 a0 = *(const short8*)&ep0[ch*32];
    short8 a1 = *(const short8*)&ep1[ch*32];
    short8 bf = *(const short8*)&wp[ch*32];
    acc0 = __builtin_amdgcn_mfma_f32_16x16x32_bf16(a0, bf, acc0, 0,0,0);
    acc1 = __builtin_amdgcn_mfma_f32_16x16x32_bf16(a1, bf, acc1, 0,0,0);
  }
  #pragma unroll
  for (int ch = 0; ch < 16; ++ch){             // k in [128,640): h part
    short8 a0 = *(const short8*)&hp0[ch*32];
    short8 a1 = *(const short8*)&hp1[ch*32];
    short8 bf = *(const short8*)&wp[128 + ch*32];
    acc0 = __builtin_amdgcn_mfma_f32_16x16x32_bf16(a0, bf, acc0, 0,0,0);
    acc1 = __builtin_amdgcn_mfma_f32_16x16x32_bf16(a1, bf, acc1, 0,0,0);
  }

  // gate exchange through LDS (identical mapping to verified round-6 path)
  {
    const int jj = l & 7;
    const int g  = wn*2 + ((l>>3)&1);
    #pragma unroll
    for (int r = 0; r < 4; ++r){
      gsc[g][jj][wm*32 +      (l>>4)*4 + r] = acc0[r];
      gsc[g][jj][wm*32 + 16 + (l>>4)*4 + r] = acc1[r];
    }
  }
  __syncthreads();

  #pragma unroll
  for (int p = 0; p < 2; ++p){
    const int pp = tid + p*256;
    const int jj = pp & 7, bl = pp >> 3;
    const int b_ = b0 + bl, j_ = j0 + jj;
    const float hv = hist[(size_t)b_*S + t];
    const float* gdr = &gd[(size_t)b_*G];
    float gi = gsc[0][jj][bl] + gdr[       j_] + hv*Wr256[       j_];
    float gf = gsc[1][jj][bl] + gdr[ 512 + j_] + hv*Wr256[ 512 + j_];
    float gg = gsc[2][jj][bl] + gdr[1024 + j_] + hv*Wr256[1024 + j_];
    float go = gsc[3][jj][bl] + gdr[1536 + j_] + hv*Wr256[1536 + j_];
    const size_t ci = (size_t)b_*H + j_;
    float cn = sigmoidf_(gf)*c[ci] + sigmoidf_(gi)*tanhf(gg);
    float hn = sigmoidf_(go)*tanhf(cn);
    c[ci] = cn;
    hout16[ci] = __float2bfloat16(hn);
    eo16[((size_t)b_*S + t)*H + j_] = __float2bfloat16(hn);
  }
}

// ======== decoder step v4: direct-load MFMA. g = h@W16D + gdd + y*Wy + a*Wa ========
__global__ __launch_bounds__(256) void dec_step4(
    const __hip_bfloat16* __restrict__ hin,    // [B][512]
    const __hip_bfloat16* __restrict__ W16,    // [2048][512] n-major
    const float* __restrict__ gdd,
    const float* __restrict__ Wy, const float* __restrict__ Wa,
    const float* __restrict__ y, const float* __restrict__ fut,
    float* __restrict__ c,
    float* __restrict__ hout32, __hip_bfloat16* __restrict__ hout16, int t)
{
  __shared__ float gsc[4][8][66];
  const int tid = threadIdx.x;
  const int id  = blockIdx.x;
  const int xcd = id & 7, sub = id >> 3;
  const int jgrp = xcd*8 + (sub & 7);
  const int bgrp = sub >> 3;
  const int b0 = bgrp*64, j0 = jgrp*8;
  const int l  = tid & 63;
  const int wid = tid >> 6, wm = wid & 1, wn = wid >> 1;
  const int lr = l & 15, lkp = (l >> 4)*8;

  const int rowA0 = b0 + wm*32 + lr;
  const int rowA1 = rowA0 + 16;
  const int cc = wn*16 + lr;
  const int bn = (cc >> 3)*512 + j0 + (cc & 7);

  const __hip_bfloat16* hp0 = &hin[(size_t)rowA0*H + lkp];
  const __hip_bfloat16* hp1 = &hin[(size_t)rowA1*H + lkp];
  const __hip_bfloat16* wp  = &W16[(size_t)bn*512 + lkp];

  f32x4 acc0 = {0.f,0.f,0.f,0.f}, acc1 = {0.f,0.f,0.f,0.f};
  #pragma unroll
  for (int ch = 0; ch < 16; ++ch){
    short8 a0 = *(const short8*)&hp0[ch*32];
    short8 a1 = *(const short8*)&hp1[ch*32];
    short8 bf = *(const short8*)&wp[ch*32];
    acc0 = __builtin_amdgcn_mfma_f32_16x16x32_bf16(a0, bf, acc0, 0,0,0);
    acc1 = __builtin_amdgcn_mfma_f32_16x16x32_bf16(a1, bf, acc1, 0,0,0);
  }

  {
    const int jj = l & 7;
    const int g  = wn*2 + ((l>>3)&1);
    #pragma unroll
    for (int r = 0; r < 4; ++r){
      gsc[g][jj][wm*32 +      (l>>4)*4 + r] = acc0[r];
      gsc[g][jj][wm*32 + 16 + (l>>4)*4 + r] = acc1[r];
    }
  }
  __syncthreads();

  #pragma unroll
  for (int p = 0; p < 2; ++p){
    const int pp = tid + p*256;
    const int jj = pp & 7, bl = pp >> 3;
    const int b_ = b0 + bl, j_ = j0 + jj;
    const float yv = y[b_];
    const float av = fut[(size_t)b_*16 + t];
    const float* gdr = &gdd[(size_t)b_*G];
    float gi = gsc[0][jj][bl] + gdr[       j_] + yv*Wy[       j_] + av*Wa[       j_];
    float gf = gsc[1][jj][bl] + gdr[ 512 + j_] + yv*Wy[ 512 + j_] + av*Wa[ 512 + j_];
    float gg = gsc[2][jj][bl] + gdr[1024 + j_] + yv*Wy[1024 + j_] + av*Wa[1024 + j_];
    float go = gsc[3][jj][bl] + gdr[1536 + j_] + yv*Wy[1536 + j_] + av*Wa[1536 + j_];
    const size_t ci = (size_t)b_*H + j_;
    float cn = sigmoidf_(gf)*c[ci] + sigmoidf_(gi)*tanhf(gg);
    float hn = sigmoidf_(go)*tanhf(cn);
    c[ci] = cn;
    hout32[ci] = hn;
    hout16[ci] = __float2bfloat16(hn);
  }
}

// ---------------- propensity logits + enc_We (one pass over eo16) ----------------
__global__ __launch_bounds__(256) void prop_we_kernel(
    const __hip_bfloat16* __restrict__ eo, const float* __restrict__ propW,
    const float* __restrict__ propb, const float* __restrict__ attnW,
    float* __restrict__ prop_out, float* __restrict__ encWe)
{
  int row = blockIdx.x*4 + (threadIdx.x >> 6);
  int lane = threadIdx.x & 63;
  const __hip_bfloat16* e = &eo[(size_t)row*H];
  float ap = 0.f, aw = 0.f;
  #pragma unroll
  for (int i = 0; i < 8; ++i){
    float v = __bfloat162float(e[lane + i*64]);
    ap += v*propW[lane + i*64];
    aw += v*attnW[512 + lane + i*64];
  }
  #pragma unroll
  for (int off = 32; off; off >>= 1){ ap += __shfl_down(ap, off); aw += __shfl_down(aw, off); }
  if (lane == 0){
    prop_out[row] = ap + propb[0];
    encWe[row] = aw;
  }
}

// ---------------- attention + context + prediction (per decoder step) ----------------
__global__ __launch_bounds__(256) void attn_pred_kernel(
    const __hip_bfloat16* __restrict__ eo, const float* __restrict__ encWe,
    const float* __restrict__ h,
    const float* __restrict__ attnW, const float* __restrict__ attnb,
    const float* __restrict__ outW, const float* __restrict__ outb,
    const float* __restrict__ fut,
    float* __restrict__ y, float* __restrict__ out, int t)
{
  int b = blockIdx.x, tid = threadIdx.x;
  __shared__ float hWi[512];
  __shared__ float red[256];
  __shared__ float sc[128];
  __shared__ float smax, ssum, shWh;

  float hv0 = h[(size_t)b*H + tid];
  float hv1 = h[(size_t)b*H + 256 + tid];
  hWi[tid]       = hv0 * attnW[1024 + tid];
  hWi[tid + 256] = hv1 * attnW[1024 + 256 + tid];
  red[tid] = hv0*attnW[tid] + hv1*attnW[256 + tid];
  __syncthreads();
  for (int off = 128; off; off >>= 1){
    if (tid < off) red[tid] += red[tid + off];
    __syncthreads();
  }
  if (tid == 0) shWh = red[0];
  __syncthreads();

  // scores: vectorized — lane covers dims [lane*8, lane*8+8)
  int lane = tid & 63;
  for (int s = (tid >> 6); s < S; s += 4){
    const __hip_bfloat16* e = &eo[((size_t)b*S + s)*H];
    short8 ev = *(const short8*)&e[lane*8];
    float a = 0.f;
    #pragma unroll
    for (int i = 0; i < 8; ++i){
      const int ii = (i + lane) & 7;   // bank-spread LDS access, same product set
      float fv = __uint_as_float(((unsigned)(unsigned short)ev[ii]) << 16);
      a += fv * hWi[lane*8 + ii];
    }
    #pragma unroll
    for (int off = 32; off; off >>= 1) a += __shfl_down(a, off);
    if (lane == 0) sc[s] = tanhf(shWh + encWe[(size_t)b*S + s] + a + attnb[0]);
  }
  __syncthreads();

  if (tid < 64){
    float m = fmaxf(sc[tid], sc[tid + 64]);
    #pragma unroll
    for (int off = 32; off; off >>= 1) m = fmaxf(m, __shfl_down(m, off));
    if (tid == 0) smax = m;
  }
  __syncthreads();
  if (tid < 128){ float e = expf(sc[tid] - smax); sc[tid] = e; red[tid] = e; }
  else red[tid] = 0.f;
  __syncthreads();
  for (int off = 128; off; off >>= 1){
    if (tid < off) red[tid] += red[tid + off];
    __syncthreads();
  }
  if (tid == 0) ssum = red[0];
  __syncthreads();
  float inv = 1.f / ssum;

  // context: thread handles dims (2*tid, 2*tid+1) via one dword load per s
  float cA = 0.f, cB = 0.f;
  const int d0 = tid*2;
  for (int s = 0; s < S; ++s){
    float w = sc[s];
    unsigned u = *(const unsigned*)&eo[((size_t)b*S + s)*H + d0];
    cA += w*bflo_(u);
    cB += w*bfhi_(u);
  }
  cA *= inv; cB *= inv;

  red[tid] = hv0*outW[tid] + hv1*outW[256 + tid] + cA*outW[512 + d0] + cB*outW[512 + d0 + 1];
  __syncthreads();
  for (int off = 128; off; off >>= 1){
    if (tid < off) red[tid] += red[tid + off];
    __syncthreads();
  }
  if (tid == 0){
    float at = fut[(size_t)b*16 + t];
    float p = red[0] + at*outW[1024] + outb[0];
    y[b] = p;
    out[(size_t)b*16 + t] = p;
  }
}

extern "C" void kernel_launch(void* const* d_in, const int* in_sizes, int n_in,
                              void* d_out, int out_size, void* d_ws, size_t ws_size,
                              hipStream_t stream)
{
  const float* temporal_x = (const float*)d_in[0];
  const float* static_x   = (const float*)d_in[1];
  const float* hist       = (const float*)d_in[2];
  const float* fut        = (const float*)d_in[3];
  const float* fio        = (const float*)d_in[4];
  const float* temp_W = (const float*)d_in[5];
  const float* temp_b = (const float*)d_in[6];
  const float* stat_W = (const float*)d_in[7];
  const float* stat_b = (const float*)d_in[8];
  const float* eWih = (const float*)d_in[9];
  const float* eWhh = (const float*)d_in[10];
  const float* eb   = (const float*)d_in[11];
  const float* attnW = (const float*)d_in[12];
  const float* attnb = (const float*)d_in[13];
  const float* dWih = (const float*)d_in[14];
  const float* dWhh = (const float*)d_in[15];
  const float* dbias = (const float*)d_in[16];
  const float* outW = (const float*)d_in[17];
  const float* outb = (const float*)d_in[18];
  const float* propW = (const float*)d_in[19];
  const float* propb = (const float*)d_in[20];
  float* out = (float*)d_out;   // fp32: [B*16 preds][B*S propensity]

  // ---- workspace layout: fp32 section then bf16 section (~52.7 MB) ----
  float* ws = (float*)d_ws;
  float* ed    = ws;                           // B*128
  float* gd_e  = ed    + (size_t)B*128;        // B*G
  float* gd_d  = gd_e  + (size_t)B*G;          // B*G
  float* cb    = gd_d  + (size_t)B*G;          // B*H
  float* encWe = cb    + (size_t)B*H;          // B*S
  float* yb    = encWe + (size_t)B*S;          // B
  float* dh32  = yb    + B;                    // B*H
  __hip_bfloat16* bf = (__hip_bfloat16*)(dh32 + (size_t)B*H);
  __hip_bfloat16* ex16 = bf;                              // B*S*128
  __hip_bfloat16* eo16 = ex16 + (size_t)B*S*128;          // B*S*H
  __hip_bfloat16* h16A = eo16 + (size_t)B*S*H;            // B*H
  __hip_bfloat16* h16B = h16A + (size_t)B*H;              // B*H
  __hip_bfloat16* W16E = h16B + (size_t)B*H;              // 2048*640
  __hip_bfloat16* W16D = W16E + (size_t)G*640;            // 2048*512

  init_kernel<<<(B*H + 255)/256, 256, 0, stream>>>(cb, (unsigned*)h16A, yb, fio);
  embed_x_kernel<<<B*S, 128, 0, stream>>>(temporal_x, temp_W, temp_b, ex16);
  embed_d_kernel<<<B, 128, 0, stream>>>(static_x, stat_W, stat_b, ed);
  gd_kernel<<<dim3(B,8), 256, 0, stream>>>(ed, eWih, 128, eb, gd_e);
  gd_kernel<<<dim3(B,8), 256, 0, stream>>>(ed, dWih, 0, dbias, gd_d);
  wtrans_kernel<<<dim3(10,32), 256, 0, stream>>>(eWih, 128, eWhh, W16E, 640);
  wtrans_kernel<<<dim3(8,32),  256, 0, stream>>>(dWhh, 0,   dWhh, W16D, 512);

  const float* wr256p = eWih + (size_t)256*G;

  // encoder: t reads (t&1 ? h16B : h16A), writes the other. Final h_n in h16A.
  for (int t = 0; t < S; ++t){
    const __hip_bfloat16* hin = (t & 1) ? h16B : h16A;
    __hip_bfloat16* hout      = (t & 1) ? h16A : h16B;
    enc_step4<<<256, 256, 0, stream>>>(ex16, hin, W16E, gd_e, wr256p,
                                       hist, cb, hout, eo16, t);
  }

  prop_we_kernel<<<(B*S)/4, 256, 0, stream>>>(eo16, propW, propb, attnW, out + B*16, encWe);

  // decoder: t reads (t&1 ? h16B : h16A) — t=0 reads h16A (h_n), writes other.
  for (int t = 0; t < 16; ++t){
    const __hip_bfloat16* hin = (t & 1) ? h16B : h16A;
    __hip_bfloat16* hout      = (t & 1) ? h16A : h16B;
    dec_step4<<<256, 256, 0, stream>>>(hin, W16D, gd_d,
                                       dWih + (size_t)128*G, dWih + (size_t)129*G,
                                       yb, fut, cb, dh32, hout, t);
    attn_pred_kernel<<<B, 256, 0, stream>>>(eo16, encWe, dh32, attnW, attnb, outW, outb,
                                            fut, yb, out, t);
  }
}

// Round 9
// 1589.658 us; speedup vs baseline: 6.5234x; 1.3569x over previous
//
#include <hip/hip_runtime.h>
#include <hip/hip_bf16.h>
#include <cstddef>

#define B 256
#define S 128
#define H 512
#define G 2048

typedef __attribute__((ext_vector_type(8))) short short8;
typedef __attribute__((ext_vector_type(4))) float f32x4;

__device__ __forceinline__ float sigmoidf_(float x){ return 1.f/(1.f+expf(-x)); }
__device__ __forceinline__ float bf2f_(unsigned short u){ return __uint_as_float(((unsigned)u) << 16); }

// ---------------- init: zero c and h16A, y = future_init_outcome ----------------
__global__ void init_kernel(float* __restrict__ c, unsigned* __restrict__ h16A_u,
                            float* __restrict__ y, const float* __restrict__ fio){
  int i = blockIdx.x*blockDim.x + threadIdx.x;
  if (i < B*H) c[i] = 0.f;
  if (i < B*H/2) h16A_u[i] = 0u;      // two bf16 zeros
  if (i < B) y[i] = fio[i];
}

// ---------------- e_x = relu(temporal_x @ temp_W + temp_b) -> bf16 ----------------
__global__ __launch_bounds__(128) void embed_x_kernel(const float* __restrict__ tx,
    const float* __restrict__ W, const float* __restrict__ bvec,
    __hip_bfloat16* __restrict__ ex16){
  __shared__ float xs[64];
  int bt = blockIdx.x, j = threadIdx.x;
  if (j < 64) xs[j] = tx[(size_t)bt*64 + j];
  __syncthreads();
  float a = bvec[j];
  #pragma unroll 8
  for (int k = 0; k < 64; ++k) a += xs[k]*W[k*128 + j];
  ex16[(size_t)bt*128 + j] = __float2bfloat16(fmaxf(a, 0.f));
}

// ---------------- e_d = relu(static_x @ stat_W + stat_b) (fp32) ----------------
__global__ __launch_bounds__(128) void embed_d_kernel(const float* __restrict__ sx,
    const float* __restrict__ W, const float* __restrict__ bvec, float* __restrict__ ed){
  __shared__ float xs[32];
  int b = blockIdx.x, j = threadIdx.x;
  if (j < 32) xs[j] = sx[(size_t)b*32 + j];
  __syncthreads();
  float a = bvec[j];
  #pragma unroll 8
  for (int k = 0; k < 32; ++k) a += xs[k]*W[k*128 + j];
  ed[(size_t)b*128 + j] = fmaxf(a, 0.f);
}

// ---------------- gd = ed @ W[wrow0:wrow0+128] + bias  (B x 2048, fp32) ----------------
__global__ __launch_bounds__(256) void gd_kernel(const float* __restrict__ ed,
    const float* __restrict__ W, int wrow0, const float* __restrict__ bias,
    float* __restrict__ gd){
  __shared__ float eds[128];
  int b = blockIdx.x, tid = threadIdx.x;
  if (tid < 128) eds[tid] = ed[(size_t)b*128 + tid];
  __syncthreads();
  int n = blockIdx.y*256 + tid;
  float a = bias[n];
  #pragma unroll 8
  for (int k = 0; k < 128; ++k) a += eds[k]*W[(size_t)(wrow0 + k)*G + n];
  gd[(size_t)b*G + n] = a;
}

// ---- weight transpose to bf16 n-major: dst[n][k], src(k,n)= k<rowsA ? A[k][n] : Bm[k-rowsA][n]
__global__ __launch_bounds__(256) void wtrans_kernel(
    const float* __restrict__ A, int rowsA, const float* __restrict__ Bm,
    __hip_bfloat16* __restrict__ dst, int Ktot)
{
  __shared__ float tile[64][65];
  const int k0 = blockIdx.x*64, n0 = blockIdx.y*64;
  const int tid = threadIdx.x;
  const int tn = tid & 63, tq = tid >> 6;     // tq in 0..3
  #pragma unroll
  for (int i = 0; i < 16; ++i){
    int k = k0 + tq*16 + i;
    float v = (k < rowsA) ? A[(size_t)k*G + n0 + tn] : Bm[(size_t)(k-rowsA)*G + n0 + tn];
    tile[k - k0][tn] = v;
  }
  __syncthreads();
  #pragma unroll
  for (int i = 0; i < 16; ++i){
    int n = n0 + tq*16 + i;
    dst[(size_t)n*Ktot + k0 + tn] = __float2bfloat16(tile[tn][tq*16 + i]);
  }
}

// ======== encoder step v4: direct global->VGPR MFMA, epilogue operands prefetched ========
__global__ __launch_bounds__(256) void enc_step4(
    const __hip_bfloat16* __restrict__ ex16,   // [B][S][128]
    const __hip_bfloat16* __restrict__ hin,    // [B][512]
    const __hip_bfloat16* __restrict__ W16,    // [2048][640] n-major
    const float* __restrict__ gd,              // [B][2048]
    const float* __restrict__ Wr256,           // fp32 row Wih[256][*]
    const float* __restrict__ hist,            // [B][S]
    float* __restrict__ c,
    __hip_bfloat16* __restrict__ hout16,
    __hip_bfloat16* __restrict__ eo16, int t)
{
  __shared__ float gsc[4][8][66];
  const int tid = threadIdx.x;
  const int id  = blockIdx.x;
  const int xcd = id & 7, sub = id >> 3;
  const int jgrp = xcd*8 + (sub & 7);          // 0..63
  const int bgrp = sub >> 3;                   // 0..3
  const int b0 = bgrp*64, j0 = jgrp*8;
  const int l  = tid & 63;
  const int wid = tid >> 6, wm = wid & 1, wn = wid >> 1;
  const int lr = l & 15, lkp = (l >> 4)*8;

  // ---- prefetch epilogue operands (independent of MFMA results)
  float hv_[2], c_[2], gdv[2][4], wrv[2][4];
  #pragma unroll
  for (int p = 0; p < 2; ++p){
    const int pp = tid + p*256;
    const int jj = pp & 7, bl = pp >> 3;
    const int b_ = b0 + bl, j_ = j0 + jj;
    hv_[p] = hist[(size_t)b_*S + t];
    c_[p]  = c[(size_t)b_*H + j_];
    #pragma unroll
    for (int g = 0; g < 4; ++g){
      gdv[p][g] = gd[(size_t)b_*G + g*512 + j_];
      wrv[p][g] = Wr256[g*512 + j_];
    }
  }

  const int rowA0 = b0 + wm*32 + lr;
  const int rowA1 = rowA0 + 16;
  const int cc = wn*16 + lr;                   // 0..31
  const int bn = (cc >> 3)*512 + j0 + (cc & 7);

  const __hip_bfloat16* ep0 = &ex16[((size_t)rowA0*S + t)*128 + lkp];
  const __hip_bfloat16* ep1 = &ex16[((size_t)rowA1*S + t)*128 + lkp];
  const __hip_bfloat16* hp0 = &hin[(size_t)rowA0*H + lkp];
  const __hip_bfloat16* hp1 = &hin[(size_t)rowA1*H + lkp];
  const __hip_bfloat16* wp  = &W16[(size_t)bn*640 + lkp];

  f32x4 acc0 = {0.f,0.f,0.f,0.f}, acc1 = {0.f,0.f,0.f,0.f};
  #pragma unroll
  for (int ch = 0; ch < 4; ++ch){              // k in [0,128): ex part
    short8 a0 = *(const short8*)&ep0[ch*32];
    short8 a1 = *(const short8*)&ep1[ch*32];
    short8 bf = *(const short8*)&wp[ch*32];
    acc0 = __builtin_amdgcn_mfma_f32_16x16x32_bf16(a0, bf, acc0, 0,0,0);
    acc1 = __builtin_amdgcn_mfma_f32_16x16x32_bf16(a1, bf, acc1, 0,0,0);
  }
  #pragma unroll
  for (int ch = 0; ch < 16; ++ch){             // k in [128,640): h part
    short8 a0 = *(const short8*)&hp0[ch*32];
    short8 a1 = *(const short8*)&hp1[ch*32];
    short8 bf = *(const short8*)&wp[128 + ch*32];
    acc0 = __builtin_amdgcn_mfma_f32_16x16x32_bf16(a0, bf, acc0, 0,0,0);
    acc1 = __builtin_amdgcn_mfma_f32_16x16x32_bf16(a1, bf, acc1, 0,0,0);
  }

  // gate exchange through LDS (verified mapping)
  {
    const int jj = l & 7;
    const int g  = wn*2 + ((l>>3)&1);
    #pragma unroll
    for (int r = 0; r < 4; ++r){
      gsc[g][jj][wm*32 +      (l>>4)*4 + r] = acc0[r];
      gsc[g][jj][wm*32 + 16 + (l>>4)*4 + r] = acc1[r];
    }
  }
  __syncthreads();

  #pragma unroll
  for (int p = 0; p < 2; ++p){
    const int pp = tid + p*256;
    const int jj = pp & 7, bl = pp >> 3;
    const int b_ = b0 + bl, j_ = j0 + jj;
    float gi = gsc[0][jj][bl] + gdv[p][0] + hv_[p]*wrv[p][0];
    float gf = gsc[1][jj][bl] + gdv[p][1] + hv_[p]*wrv[p][1];
    float gg = gsc[2][jj][bl] + gdv[p][2] + hv_[p]*wrv[p][2];
    float go = gsc[3][jj][bl] + gdv[p][3] + hv_[p]*wrv[p][3];
    const size_t ci = (size_t)b_*H + j_;
    float cn = sigmoidf_(gf)*c_[p] + sigmoidf_(gi)*tanhf(gg);
    float hn = sigmoidf_(go)*tanhf(cn);
    c[ci] = cn;
    hout16[ci] = __float2bfloat16(hn);
    eo16[((size_t)b_*S + t)*H + j_] = __float2bfloat16(hn);
  }
}

// ======== decoder step v4: direct-load MFMA, epilogue operands prefetched ========
__global__ __launch_bounds__(256) void dec_step4(
    const __hip_bfloat16* __restrict__ hin,    // [B][512]
    const __hip_bfloat16* __restrict__ W16,    // [2048][512] n-major
    const float* __restrict__ gdd,
    const float* __restrict__ Wy, const float* __restrict__ Wa,
    const float* __restrict__ y, const float* __restrict__ fut,
    float* __restrict__ c,
    float* __restrict__ hout32, __hip_bfloat16* __restrict__ hout16, int t)
{
  __shared__ float gsc[4][8][66];
  const int tid = threadIdx.x;
  const int id  = blockIdx.x;
  const int xcd = id & 7, sub = id >> 3;
  const int jgrp = xcd*8 + (sub & 7);
  const int bgrp = sub >> 3;
  const int b0 = bgrp*64, j0 = jgrp*8;
  const int l  = tid & 63;
  const int wid = tid >> 6, wm = wid & 1, wn = wid >> 1;
  const int lr = l & 15, lkp = (l >> 4)*8;

  // ---- prefetch epilogue operands
  float yv_[2], av_[2], c_[2], gdv[2][4], wyv[2][4], wav[2][4];
  #pragma unroll
  for (int p = 0; p < 2; ++p){
    const int pp = tid + p*256;
    const int jj = pp & 7, bl = pp >> 3;
    const int b_ = b0 + bl, j_ = j0 + jj;
    yv_[p] = y[b_];
    av_[p] = fut[(size_t)b_*16 + t];
    c_[p]  = c[(size_t)b_*H + j_];
    #pragma unroll
    for (int g = 0; g < 4; ++g){
      gdv[p][g] = gdd[(size_t)b_*G + g*512 + j_];
      wyv[p][g] = Wy[g*512 + j_];
      wav[p][g] = Wa[g*512 + j_];
    }
  }

  const int rowA0 = b0 + wm*32 + lr;
  const int rowA1 = rowA0 + 16;
  const int cc = wn*16 + lr;
  const int bn = (cc >> 3)*512 + j0 + (cc & 7);

  const __hip_bfloat16* hp0 = &hin[(size_t)rowA0*H + lkp];
  const __hip_bfloat16* hp1 = &hin[(size_t)rowA1*H + lkp];
  const __hip_bfloat16* wp  = &W16[(size_t)bn*512 + lkp];

  f32x4 acc0 = {0.f,0.f,0.f,0.f}, acc1 = {0.f,0.f,0.f,0.f};
  #pragma unroll
  for (int ch = 0; ch < 16; ++ch){
    short8 a0 = *(const short8*)&hp0[ch*32];
    short8 a1 = *(const short8*)&hp1[ch*32];
    short8 bf = *(const short8*)&wp[ch*32];
    acc0 = __builtin_amdgcn_mfma_f32_16x16x32_bf16(a0, bf, acc0, 0,0,0);
    acc1 = __builtin_amdgcn_mfma_f32_16x16x32_bf16(a1, bf, acc1, 0,0,0);
  }

  {
    const int jj = l & 7;
    const int g  = wn*2 + ((l>>3)&1);
    #pragma unroll
    for (int r = 0; r < 4; ++r){
      gsc[g][jj][wm*32 +      (l>>4)*4 + r] = acc0[r];
      gsc[g][jj][wm*32 + 16 + (l>>4)*4 + r] = acc1[r];
    }
  }
  __syncthreads();

  #pragma unroll
  for (int p = 0; p < 2; ++p){
    const int pp = tid + p*256;
    const int jj = pp & 7, bl = pp >> 3;
    const int b_ = b0 + bl, j_ = j0 + jj;
    float gi = gsc[0][jj][bl] + gdv[p][0] + yv_[p]*wyv[p][0] + av_[p]*wav[p][0];
    float gf = gsc[1][jj][bl] + gdv[p][1] + yv_[p]*wyv[p][1] + av_[p]*wav[p][1];
    float gg = gsc[2][jj][bl] + gdv[p][2] + yv_[p]*wyv[p][2] + av_[p]*wav[p][2];
    float go = gsc[3][jj][bl] + gdv[p][3] + yv_[p]*wyv[p][3] + av_[p]*wav[p][3];
    const size_t ci = (size_t)b_*H + j_;
    float cn = sigmoidf_(gf)*c_[p] + sigmoidf_(gi)*tanhf(gg);
    float hn = sigmoidf_(go)*tanhf(cn);
    c[ci] = cn;
    hout32[ci] = hn;
    hout16[ci] = __float2bfloat16(hn);
  }
}

// ------- propensity + enc_We + nu (nu_bs = eo_bs . outW[512:1024]) in one pass -------
__global__ __launch_bounds__(256) void prop_we_kernel(
    const __hip_bfloat16* __restrict__ eo, const float* __restrict__ propW,
    const float* __restrict__ propb, const float* __restrict__ attnW,
    const float* __restrict__ owc,             // outW + 512
    float* __restrict__ prop_out, float* __restrict__ encWe,
    float* __restrict__ nu)
{
  int row = blockIdx.x*4 + (threadIdx.x >> 6);
  int lane = threadIdx.x & 63;
  const __hip_bfloat16* e = &eo[(size_t)row*H];
  float ap = 0.f, aw = 0.f, an = 0.f;
  #pragma unroll
  for (int i = 0; i < 8; ++i){
    float v = __bfloat162float(e[lane + i*64]);
    ap += v*propW[lane + i*64];
    aw += v*attnW[512 + lane + i*64];
    an += v*owc[lane + i*64];
  }
  #pragma unroll
  for (int off = 32; off; off >>= 1){
    ap += __shfl_down(ap, off); aw += __shfl_down(aw, off); an += __shfl_down(an, off);
  }
  if (lane == 0){
    prop_out[row] = ap + propb[0];
    encWe[row] = aw;
    nu[row] = an;
  }
}

// ---------------- attention v2: scores pass only; context folded into nu-dot ----------------
__global__ __launch_bounds__(256) void attn_pred2(
    const __hip_bfloat16* __restrict__ eo, const float* __restrict__ encWe,
    const float* __restrict__ nu, const float* __restrict__ h,
    const float* __restrict__ attnW, const float* __restrict__ attnb,
    const float* __restrict__ outW, const float* __restrict__ outb,
    const float* __restrict__ fut,
    float* __restrict__ y, float* __restrict__ out, int t)
{
  __shared__ float hWi[512];
  __shared__ float sc[128];
  __shared__ float enl[128], nul[128];
  __shared__ float wpart[4];
  __shared__ float smax_s, ssum_s, sdot_s;
  const int b = blockIdx.x, tid = threadIdx.x;
  const int l = tid & 63, wid = tid >> 6;

  float hv0 = h[(size_t)b*H + tid];
  float hv1 = h[(size_t)b*H + 256 + tid];
  hWi[tid]       = hv0 * attnW[1024 + tid];
  hWi[tid + 256] = hv1 * attnW[1280 + tid];
  if (tid < 128) enl[tid] = encWe[(size_t)b*S + tid];
  else           nul[tid - 128] = nu[(size_t)b*S + tid - 128];

  // shWh partials (wave reduce, one barrier)
  float r = hv0*attnW[tid] + hv1*attnW[256 + tid];
  #pragma unroll
  for (int off = 32; off; off >>= 1) r += __shfl_down(r, off);
  if (l == 0) wpart[wid] = r;
  __syncthreads();
  const float sWh = wpart[0] + wpart[1] + wpart[2] + wpart[3] + attnb[0];

  // scores: wave owns s in [wid*32, wid*32+32); 8-lane group per s.
  // lane covers dims {(l&7)*8 + i*64}, i=0..7  -> 8 independent 16B loads,
  // each instruction = 8 rows x 128B contiguous.
  const int sg  = l >> 3;
  const int dlo = (l & 7) * 8;
  #pragma unroll
  for (int p = 0; p < 4; ++p){
    const int s = wid*32 + p*8 + sg;
    const __hip_bfloat16* erow = &eo[((size_t)b*S + s)*H];
    short8 ev[8];
    #pragma unroll
    for (int i = 0; i < 8; ++i) ev[i] = *(const short8*)&erow[dlo + i*64];
    float a = 0.f;
    #pragma unroll
    for (int i = 0; i < 8; ++i){
      #pragma unroll
      for (int k = 0; k < 8; ++k)
        a += bf2f_((unsigned short)ev[i][k]) * hWi[dlo + i*64 + k];
    }
    a += __shfl_xor(a, 4);
    a += __shfl_xor(a, 2);
    a += __shfl_xor(a, 1);
    if ((l & 7) == 0) sc[s] = tanhf(sWh + enl[s] + a);
  }
  __syncthreads();

  // softmax max
  if (tid < 64){
    float m = fmaxf(sc[tid], sc[tid + 64]);
    #pragma unroll
    for (int off = 32; off; off >>= 1) m = fmaxf(m, __shfl_down(m, off));
    if (tid == 0) smax_s = m;
  }
  __syncthreads();
  // exp, sum, nu-dot in one reduction
  if (tid < 64){
    float e0 = expf(sc[tid] - smax_s), e1 = expf(sc[tid + 64] - smax_s);
    float ss = e0 + e1;
    float sd = e0*nul[tid] + e1*nul[tid + 64];
    #pragma unroll
    for (int off = 32; off; off >>= 1){ ss += __shfl_down(ss, off); sd += __shfl_down(sd, off); }
    if (tid == 0){ ssum_s = ss; sdot_s = sd; }
  }

  // pred partials: h . outW[0:512]
  float r2 = hv0*outW[tid] + hv1*outW[256 + tid];
  #pragma unroll
  for (int off = 32; off; off >>= 1) r2 += __shfl_down(r2, off);
  __syncthreads();
  if (l == 0) wpart[wid] = r2;
  __syncthreads();
  if (tid == 0){
    float at = fut[(size_t)b*16 + t];
    float p = wpart[0] + wpart[1] + wpart[2] + wpart[3]
            + sdot_s / ssum_s + at*outW[1024] + outb[0];
    y[b] = p;
    out[(size_t)b*16 + t] = p;
  }
}

extern "C" void kernel_launch(void* const* d_in, const int* in_sizes, int n_in,
                              void* d_out, int out_size, void* d_ws, size_t ws_size,
                              hipStream_t stream)
{
  const float* temporal_x = (const float*)d_in[0];
  const float* static_x   = (const float*)d_in[1];
  const float* hist       = (const float*)d_in[2];
  const float* fut        = (const float*)d_in[3];
  const float* fio        = (const float*)d_in[4];
  const float* temp_W = (const float*)d_in[5];
  const float* temp_b = (const float*)d_in[6];
  const float* stat_W = (const float*)d_in[7];
  const float* stat_b = (const float*)d_in[8];
  const float* eWih = (const float*)d_in[9];
  const float* eWhh = (const float*)d_in[10];
  const float* eb   = (const float*)d_in[11];
  const float* attnW = (const float*)d_in[12];
  const float* attnb = (const float*)d_in[13];
  const float* dWih = (const float*)d_in[14];
  const float* dWhh = (const float*)d_in[15];
  const float* dbias = (const float*)d_in[16];
  const float* outW = (const float*)d_in[17];
  const float* outb = (const float*)d_in[18];
  const float* propW = (const float*)d_in[19];
  const float* propb = (const float*)d_in[20];
  float* out = (float*)d_out;   // fp32: [B*16 preds][B*S propensity]

  // ---- workspace layout: fp32 section then bf16 section (~52.9 MB) ----
  float* ws = (float*)d_ws;
  float* ed    = ws;                           // B*128
  float* gd_e  = ed    + (size_t)B*128;        // B*G
  float* gd_d  = gd_e  + (size_t)B*G;          // B*G
  float* cb    = gd_d  + (size_t)B*G;          // B*H
  float* encWe = cb    + (size_t)B*H;          // B*S
  float* nub   = encWe + (size_t)B*S;          // B*S
  float* yb    = nub   + (size_t)B*S;          // B
  float* dh32  = yb    + B;                    // B*H
  __hip_bfloat16* bf = (__hip_bfloat16*)(dh32 + (size_t)B*H);
  __hip_bfloat16* ex16 = bf;                              // B*S*128
  __hip_bfloat16* eo16 = ex16 + (size_t)B*S*128;          // B*S*H
  __hip_bfloat16* h16A = eo16 + (size_t)B*S*H;            // B*H
  __hip_bfloat16* h16B = h16A + (size_t)B*H;              // B*H
  __hip_bfloat16* W16E = h16B + (size_t)B*H;              // 2048*640
  __hip_bfloat16* W16D = W16E + (size_t)G*640;            // 2048*512

  init_kernel<<<(B*H + 255)/256, 256, 0, stream>>>(cb, (unsigned*)h16A, yb, fio);
  embed_x_kernel<<<B*S, 128, 0, stream>>>(temporal_x, temp_W, temp_b, ex16);
  embed_d_kernel<<<B, 128, 0, stream>>>(static_x, stat_W, stat_b, ed);
  gd_kernel<<<dim3(B,8), 256, 0, stream>>>(ed, eWih, 128, eb, gd_e);
  gd_kernel<<<dim3(B,8), 256, 0, stream>>>(ed, dWih, 0, dbias, gd_d);
  wtrans_kernel<<<dim3(10,32), 256, 0, stream>>>(eWih, 128, eWhh, W16E, 640);
  wtrans_kernel<<<dim3(8,32),  256, 0, stream>>>(dWhh, 0,   dWhh, W16D, 512);

  const float* wr256p = eWih + (size_t)256*G;

  // encoder: t reads (t&1 ? h16B : h16A), writes the other. Final h_n in h16A.
  for (int t = 0; t < S; ++t){
    const __hip_bfloat16* hin = (t & 1) ? h16B : h16A;
    __hip_bfloat16* hout      = (t & 1) ? h16A : h16B;
    enc_step4<<<256, 256, 0, stream>>>(ex16, hin, W16E, gd_e, wr256p,
                                       hist, cb, hout, eo16, t);
  }

  prop_we_kernel<<<(B*S)/4, 256, 0, stream>>>(eo16, propW, propb, attnW, outW + 512,
                                              out + B*16, encWe, nub);

  // decoder: t reads (t&1 ? h16B : h16A) — t=0 reads h16A (h_n), writes other.
  for (int t = 0; t < 16; ++t){
    const __hip_bfloat16* hin = (t & 1) ? h16B : h16A;
    __hip_bfloat16* hout      = (t & 1) ? h16A : h16B;
    dec_step4<<<256, 256, 0, stream>>>(hin, W16D, gd_d,
                                       dWih + (size_t)128*G, dWih + (size_t)129*G,
                                       yb, fut, cb, dh32, hout, t);
    attn_pred2<<<B, 256, 0, stream>>>(eo16, encWe, nub, dh32, attnW, attnb, outW, outb,
                                      fut, yb, out, t);
  }
}

// Round 10
// 1563.414 us; speedup vs baseline: 6.6329x; 1.0168x over previous
//
#include <hip/hip_runtime.h>
#include <hip/hip_bf16.h>
#include <cstddef>

#define B 256
#define S 128
#define H 512
#define G 2048

typedef __attribute__((ext_vector_type(8))) short short8;
typedef __attribute__((ext_vector_type(4))) float f32x4;

__device__ __forceinline__ float sigmoidf_(float x){ return 1.f/(1.f+expf(-x)); }
__device__ __forceinline__ float bf2f_(unsigned short u){ return __uint_as_float(((unsigned)u) << 16); }

// ---------------- init: zero c and h16A, y = future_init_outcome ----------------
__global__ void init_kernel(float* __restrict__ c, unsigned* __restrict__ h16A_u,
                            float* __restrict__ y, const float* __restrict__ fio){
  int i = blockIdx.x*blockDim.x + threadIdx.x;
  if (i < B*H) c[i] = 0.f;
  if (i < B*H/2) h16A_u[i] = 0u;      // two bf16 zeros (enc t=0 reads h=0)
  if (i < B) y[i] = fio[i];
}

// ------- e_x = relu(temporal_x @ temp_W + temp_b) -> bf16, W cached in LDS -------
__global__ __launch_bounds__(256) void embed_x2(const float* __restrict__ tx,
    const float* __restrict__ W, const float* __restrict__ bvec,
    __hip_bfloat16* __restrict__ ex16){
  __shared__ float Ws[64][128];     // 32 KB, loaded once per block
  __shared__ float bs[128];
  __shared__ float xs[4][64];
  const int tid = threadIdx.x;
  for (int i = tid; i < 64*128; i += 256) Ws[i>>7][i&127] = W[i];
  if (tid < 128) bs[tid] = bvec[tid];
  __syncthreads();

  const int r0 = blockIdx.x * 128;            // 256 blocks x 128 rows = 32768
  const int j  = tid & 127, pr = tid >> 7;    // pr in {0,1}
  for (int rr = 0; rr < 128; rr += 4){
    xs[tid>>6][tid&63] = tx[(size_t)(r0 + rr + (tid>>6))*64 + (tid&63)];
    __syncthreads();
    #pragma unroll
    for (int q = 0; q < 2; ++q){
      const int row = pr + q*2;
      float a = bs[j];
      #pragma unroll 16
      for (int k = 0; k < 64; ++k) a += xs[row][k]*Ws[k][j];
      ex16[(size_t)(r0 + rr + row)*128 + j] = __float2bfloat16(fmaxf(a, 0.f));
    }
    __syncthreads();
  }
}

// ---------------- e_d = relu(static_x @ stat_W + stat_b) (fp32) ----------------
__global__ __launch_bounds__(128) void embed_d_kernel(const float* __restrict__ sx,
    const float* __restrict__ W, const float* __restrict__ bvec, float* __restrict__ ed){
  __shared__ float xs[32];
  int b = blockIdx.x, j = threadIdx.x;
  if (j < 32) xs[j] = sx[(size_t)b*32 + j];
  __syncthreads();
  float a = bvec[j];
  #pragma unroll 8
  for (int k = 0; k < 32; ++k) a += xs[k]*W[k*128 + j];
  ed[(size_t)b*128 + j] = fmaxf(a, 0.f);
}

// ---------------- gd = ed @ W[wrow0:wrow0+128] + bias  (B x 2048, fp32) ----------------
__global__ __launch_bounds__(256) void gd_kernel(const float* __restrict__ ed,
    const float* __restrict__ W, int wrow0, const float* __restrict__ bias,
    float* __restrict__ gd){
  __shared__ float eds[128];
  int b = blockIdx.x, tid = threadIdx.x;
  if (tid < 128) eds[tid] = ed[(size_t)b*128 + tid];
  __syncthreads();
  int n = blockIdx.y*256 + tid;
  float a = bias[n];
  #pragma unroll 8
  for (int k = 0; k < 128; ++k) a += eds[k]*W[(size_t)(wrow0 + k)*G + n];
  gd[(size_t)b*G + n] = a;
}

// ---- weight transpose to bf16 n-major: dst[n][k], src(k,n)= k<rowsA ? A[k][n] : Bm[k-rowsA][n]
__global__ __launch_bounds__(256) void wtrans_kernel(
    const float* __restrict__ A, int rowsA, const float* __restrict__ Bm,
    __hip_bfloat16* __restrict__ dst, int Ktot)
{
  __shared__ float tile[64][65];
  const int k0 = blockIdx.x*64, n0 = blockIdx.y*64;
  const int tid = threadIdx.x;
  const int tn = tid & 63, tq = tid >> 6;     // tq in 0..3
  #pragma unroll
  for (int i = 0; i < 16; ++i){
    int k = k0 + tq*16 + i;
    float v = (k < rowsA) ? A[(size_t)k*G + n0 + tn] : Bm[(size_t)(k-rowsA)*G + n0 + tn];
    tile[k - k0][tn] = v;
  }
  __syncthreads();
  #pragma unroll
  for (int i = 0; i < 16; ++i){
    int n = n0 + tq*16 + i;
    dst[(size_t)n*Ktot + k0 + tn] = __float2bfloat16(tile[tn][tq*16 + i]);
  }
}

// ======== encoder step v5: direct global->VGPR MFMA; h read from eo16 slice ========
__global__ __launch_bounds__(256) void enc_step5(
    const __hip_bfloat16* __restrict__ ex16,   // [B][S][128]
    const __hip_bfloat16* __restrict__ hin,    // h(t-1), row stride hs
    int hs,
    const __hip_bfloat16* __restrict__ W16,    // [2048][640] n-major
    const float* __restrict__ gd,              // [B][2048]
    const float* __restrict__ Wr256,           // fp32 row Wih[256][*]
    const float* __restrict__ hist,            // [B][S]
    float* __restrict__ c,
    __hip_bfloat16* __restrict__ eo16, int t)
{
  __shared__ float gsc[4][8][66];
  const int tid = threadIdx.x;
  const int id  = blockIdx.x;
  const int xcd = id & 7, sub = id >> 3;
  const int jgrp = xcd*8 + (sub & 7);          // 0..63
  const int bgrp = sub >> 3;                   // 0..3
  const int b0 = bgrp*64, j0 = jgrp*8;
  const int l  = tid & 63;
  const int wid = tid >> 6, wm = wid & 1, wn = wid >> 1;
  const int lr = l & 15, lkp = (l >> 4)*8;

  // ---- prefetch epilogue operands (independent of MFMA results)
  float hv_[2], c_[2], gdv[2][4], wrv[2][4];
  #pragma unroll
  for (int p = 0; p < 2; ++p){
    const int pp = tid + p*256;
    const int jj = pp & 7, bl = pp >> 3;
    const int b_ = b0 + bl, j_ = j0 + jj;
    hv_[p] = hist[(size_t)b_*S + t];
    c_[p]  = c[(size_t)b_*H + j_];
    #pragma unroll
    for (int g = 0; g < 4; ++g){
      gdv[p][g] = gd[(size_t)b_*G + g*512 + j_];
      wrv[p][g] = Wr256[g*512 + j_];
    }
  }

  const int rowA0 = b0 + wm*32 + lr;
  const int rowA1 = rowA0 + 16;
  const int cc = wn*16 + lr;                   // 0..31
  const int bn = (cc >> 3)*512 + j0 + (cc & 7);

  const __hip_bfloat16* ep0 = &ex16[((size_t)rowA0*S + t)*128 + lkp];
  const __hip_bfloat16* ep1 = &ex16[((size_t)rowA1*S + t)*128 + lkp];
  const __hip_bfloat16* hp0 = &hin[(size_t)rowA0*hs + lkp];
  const __hip_bfloat16* hp1 = &hin[(size_t)rowA1*hs + lkp];
  const __hip_bfloat16* wp  = &W16[(size_t)bn*640 + lkp];

  f32x4 acc0 = {0.f,0.f,0.f,0.f}, acc1 = {0.f,0.f,0.f,0.f};
  #pragma unroll
  for (int ch = 0; ch < 4; ++ch){              // k in [0,128): ex part
    short8 a0 = *(const short8*)&ep0[ch*32];
    short8 a1 = *(const short8*)&ep1[ch*32];
    short8 bf = *(const short8*)&wp[ch*32];
    acc0 = __builtin_amdgcn_mfma_f32_16x16x32_bf16(a0, bf, acc0, 0,0,0);
    acc1 = __builtin_amdgcn_mfma_f32_16x16x32_bf16(a1, bf, acc1, 0,0,0);
  }
  #pragma unroll
  for (int ch = 0; ch < 16; ++ch){             // k in [128,640): h part
    short8 a0 = *(const short8*)&hp0[ch*32];
    short8 a1 = *(const short8*)&hp1[ch*32];
    short8 bf = *(const short8*)&wp[128 + ch*32];
    acc0 = __builtin_amdgcn_mfma_f32_16x16x32_bf16(a0, bf, acc0, 0,0,0);
    acc1 = __builtin_amdgcn_mfma_f32_16x16x32_bf16(a1, bf, acc1, 0,0,0);
  }

  // gate exchange through LDS (verified mapping)
  {
    const int jj = l & 7;
    const int g  = wn*2 + ((l>>3)&1);
    #pragma unroll
    for (int r = 0; r < 4; ++r){
      gsc[g][jj][wm*32 +      (l>>4)*4 + r] = acc0[r];
      gsc[g][jj][wm*32 + 16 + (l>>4)*4 + r] = acc1[r];
    }
  }
  __syncthreads();

  #pragma unroll
  for (int p = 0; p < 2; ++p){
    const int pp = tid + p*256;
    const int jj = pp & 7, bl = pp >> 3;
    const int b_ = b0 + bl, j_ = j0 + jj;
    float gi = gsc[0][jj][bl] + gdv[p][0] + hv_[p]*wrv[p][0];
    float gf = gsc[1][jj][bl] + gdv[p][1] + hv_[p]*wrv[p][1];
    float gg = gsc[2][jj][bl] + gdv[p][2] + hv_[p]*wrv[p][2];
    float go = gsc[3][jj][bl] + gdv[p][3] + hv_[p]*wrv[p][3];
    const size_t ci = (size_t)b_*H + j_;
    float cn = sigmoidf_(gf)*c_[p] + sigmoidf_(gi)*tanhf(gg);
    float hn = sigmoidf_(go)*tanhf(cn);
    c[ci] = cn;
    eo16[((size_t)b_*S + t)*H + j_] = __float2bfloat16(hn);
  }
}

// ======== decoder step v5: direct-load MFMA; hin has row stride hs ========
__global__ __launch_bounds__(256) void dec_step5(
    const __hip_bfloat16* __restrict__ hin, int hs,
    const __hip_bfloat16* __restrict__ W16,    // [2048][512] n-major
    const float* __restrict__ gdd,
    const float* __restrict__ Wy, const float* __restrict__ Wa,
    const float* __restrict__ y, const float* __restrict__ fut,
    float* __restrict__ c,
    float* __restrict__ hout32, __hip_bfloat16* __restrict__ hout16, int t)
{
  __shared__ float gsc[4][8][66];
  const int tid = threadIdx.x;
  const int id  = blockIdx.x;
  const int xcd = id & 7, sub = id >> 3;
  const int jgrp = xcd*8 + (sub & 7);
  const int bgrp = sub >> 3;
  const int b0 = bgrp*64, j0 = jgrp*8;
  const int l  = tid & 63;
  const int wid = tid >> 6, wm = wid & 1, wn = wid >> 1;
  const int lr = l & 15, lkp = (l >> 4)*8;

  // ---- prefetch epilogue operands
  float yv_[2], av_[2], c_[2], gdv[2][4], wyv[2][4], wav[2][4];
  #pragma unroll
  for (int p = 0; p < 2; ++p){
    const int pp = tid + p*256;
    const int jj = pp & 7, bl = pp >> 3;
    const int b_ = b0 + bl, j_ = j0 + jj;
    yv_[p] = y[b_];
    av_[p] = fut[(size_t)b_*16 + t];
    c_[p]  = c[(size_t)b_*H + j_];
    #pragma unroll
    for (int g = 0; g < 4; ++g){
      gdv[p][g] = gdd[(size_t)b_*G + g*512 + j_];
      wyv[p][g] = Wy[g*512 + j_];
      wav[p][g] = Wa[g*512 + j_];
    }
  }

  const int rowA0 = b0 + wm*32 + lr;
  const int rowA1 = rowA0 + 16;
  const int cc = wn*16 + lr;
  const int bn = (cc >> 3)*512 + j0 + (cc & 7);

  const __hip_bfloat16* hp0 = &hin[(size_t)rowA0*hs + lkp];
  const __hip_bfloat16* hp1 = &hin[(size_t)rowA1*hs + lkp];
  const __hip_bfloat16* wp  = &W16[(size_t)bn*512 + lkp];

  f32x4 acc0 = {0.f,0.f,0.f,0.f}, acc1 = {0.f,0.f,0.f,0.f};
  #pragma unroll
  for (int ch = 0; ch < 16; ++ch){
    short8 a0 = *(const short8*)&hp0[ch*32];
    short8 a1 = *(const short8*)&hp1[ch*32];
    short8 bf = *(const short8*)&wp[ch*32];
    acc0 = __builtin_amdgcn_mfma_f32_16x16x32_bf16(a0, bf, acc0, 0,0,0);
    acc1 = __builtin_amdgcn_mfma_f32_16x16x32_bf16(a1, bf, acc1, 0,0,0);
  }

  {
    const int jj = l & 7;
    const int g  = wn*2 + ((l>>3)&1);
    #pragma unroll
    for (int r = 0; r < 4; ++r){
      gsc[g][jj][wm*32 +      (l>>4)*4 + r] = acc0[r];
      gsc[g][jj][wm*32 + 16 + (l>>4)*4 + r] = acc1[r];
    }
  }
  __syncthreads();

  #pragma unroll
  for (int p = 0; p < 2; ++p){
    const int pp = tid + p*256;
    const int jj = pp & 7, bl = pp >> 3;
    const int b_ = b0 + bl, j_ = j0 + jj;
    float gi = gsc[0][jj][bl] + gdv[p][0] + yv_[p]*wyv[p][0] + av_[p]*wav[p][0];
    float gf = gsc[1][jj][bl] + gdv[p][1] + yv_[p]*wyv[p][1] + av_[p]*wav[p][1];
    float gg = gsc[2][jj][bl] + gdv[p][2] + yv_[p]*wyv[p][2] + av_[p]*wav[p][2];
    float go = gsc[3][jj][bl] + gdv[p][3] + yv_[p]*wyv[p][3] + av_[p]*wav[p][3];
    const size_t ci = (size_t)b_*H + j_;
    float cn = sigmoidf_(gf)*c_[p] + sigmoidf_(gi)*tanhf(gg);
    float hn = sigmoidf_(go)*tanhf(cn);
    c[ci] = cn;
    hout32[ci] = hn;
    hout16[ci] = __float2bfloat16(hn);
  }
}

// ------- propensity + enc_We + nu (nu_bs = eo_bs . outW[512:1024]) in one pass -------
__global__ __launch_bounds__(256) void prop_we_kernel(
    const __hip_bfloat16* __restrict__ eo, const float* __restrict__ propW,
    const float* __restrict__ propb, const float* __restrict__ attnW,
    const float* __restrict__ owc,             // outW + 512
    float* __restrict__ prop_out, float* __restrict__ encWe,
    float* __restrict__ nu)
{
  int row = blockIdx.x*4 + (threadIdx.x >> 6);
  int lane = threadIdx.x & 63;
  const __hip_bfloat16* e = &eo[(size_t)row*H];
  float ap = 0.f, aw = 0.f, an = 0.f;
  #pragma unroll
  for (int i = 0; i < 8; ++i){
    float v = __bfloat162float(e[lane + i*64]);
    ap += v*propW[lane + i*64];
    aw += v*attnW[512 + lane + i*64];
    an += v*owc[lane + i*64];
  }
  #pragma unroll
  for (int off = 32; off; off >>= 1){
    ap += __shfl_down(ap, off); aw += __shfl_down(aw, off); an += __shfl_down(an, off);
  }
  if (lane == 0){
    prop_out[row] = ap + propb[0];
    encWe[row] = aw;
    nu[row] = an;
  }
}

// ---------------- attention v3: 512 threads, scores pass + nu-dot ----------------
__global__ __launch_bounds__(512) void attn_pred3(
    const __hip_bfloat16* __restrict__ eo, const float* __restrict__ encWe,
    const float* __restrict__ nu, const float* __restrict__ h,
    const float* __restrict__ attnW, const float* __restrict__ attnb,
    const float* __restrict__ outW, const float* __restrict__ outb,
    const float* __restrict__ fut,
    float* __restrict__ y, float* __restrict__ out, int t)
{
  __shared__ float hWi[512];
  __shared__ float sc[128];
  __shared__ float enl[128], nul[128];
  __shared__ float wpart[8];
  __shared__ float smax_s, ssum_s, sdot_s;
  const int b = blockIdx.x, tid = threadIdx.x;
  const int l = tid & 63, wid = tid >> 6;     // 8 waves

  const float hv = h[(size_t)b*H + tid];
  hWi[tid] = hv * attnW[1024 + tid];
  if (tid < 128) enl[tid] = encWe[(size_t)b*S + tid];
  else if (tid < 256) nul[tid - 128] = nu[(size_t)b*S + tid - 128];

  // h . attnW[0:512] partials
  float r = hv * attnW[tid];
  #pragma unroll
  for (int off = 32; off; off >>= 1) r += __shfl_down(r, off);
  if (l == 0) wpart[wid] = r;
  __syncthreads();
  float sWh = attnb[0];
  #pragma unroll
  for (int w = 0; w < 8; ++w) sWh += wpart[w];

  // scores: 8-lane group per s; 64 s per pass, 2 passes
  const int sg  = l >> 3;
  const int dlo = (l & 7) * 8;
  #pragma unroll
  for (int p = 0; p < 2; ++p){
    const int s = p*64 + wid*8 + sg;
    const __hip_bfloat16* erow = &eo[((size_t)b*S + s)*H];
    short8 ev[8];
    #pragma unroll
    for (int i = 0; i < 8; ++i) ev[i] = *(const short8*)&erow[dlo + i*64];
    float a = 0.f;
    #pragma unroll
    for (int i = 0; i < 8; ++i){
      #pragma unroll
      for (int k = 0; k < 8; ++k)
        a += bf2f_((unsigned short)ev[i][k]) * hWi[dlo + i*64 + k];
    }
    a += __shfl_xor(a, 4);
    a += __shfl_xor(a, 2);
    a += __shfl_xor(a, 1);
    if ((l & 7) == 0) sc[s] = tanhf(sWh + enl[s] + a);
  }
  __syncthreads();

  // softmax max
  if (tid < 64){
    float m = fmaxf(sc[tid], sc[tid + 64]);
    #pragma unroll
    for (int off = 32; off; off >>= 1) m = fmaxf(m, __shfl_down(m, off));
    if (tid == 0) smax_s = m;
  }
  __syncthreads();
  // exp, sum, nu-dot in one wave
  if (tid < 64){
    float e0 = expf(sc[tid] - smax_s), e1 = expf(sc[tid + 64] - smax_s);
    float ss = e0 + e1;
    float sd = e0*nul[tid] + e1*nul[tid + 64];
    #pragma unroll
    for (int off = 32; off; off >>= 1){ ss += __shfl_down(ss, off); sd += __shfl_down(sd, off); }
    if (tid == 0){ ssum_s = ss; sdot_s = sd; }
  }

  // pred partials: h . outW[0:512]
  float r2 = hv * outW[tid];
  #pragma unroll
  for (int off = 32; off; off >>= 1) r2 += __shfl_down(r2, off);
  __syncthreads();
  if (l == 0) wpart[wid] = r2;
  __syncthreads();
  if (tid == 0){
    float at = fut[(size_t)b*16 + t];
    float p = wpart[0]+wpart[1]+wpart[2]+wpart[3]+wpart[4]+wpart[5]+wpart[6]+wpart[7]
            + sdot_s / ssum_s + at*outW[1024] + outb[0];
    y[b] = p;
    out[(size_t)b*16 + t] = p;
  }
}

extern "C" void kernel_launch(void* const* d_in, const int* in_sizes, int n_in,
                              void* d_out, int out_size, void* d_ws, size_t ws_size,
                              hipStream_t stream)
{
  const float* temporal_x = (const float*)d_in[0];
  const float* static_x   = (const float*)d_in[1];
  const float* hist       = (const float*)d_in[2];
  const float* fut        = (const float*)d_in[3];
  const float* fio        = (const float*)d_in[4];
  const float* temp_W = (const float*)d_in[5];
  const float* temp_b = (const float*)d_in[6];
  const float* stat_W = (const float*)d_in[7];
  const float* stat_b = (const float*)d_in[8];
  const float* eWih = (const float*)d_in[9];
  const float* eWhh = (const float*)d_in[10];
  const float* eb   = (const float*)d_in[11];
  const float* attnW = (const float*)d_in[12];
  const float* attnb = (const float*)d_in[13];
  const float* dWih = (const float*)d_in[14];
  const float* dWhh = (const float*)d_in[15];
  const float* dbias = (const float*)d_in[16];
  const float* outW = (const float*)d_in[17];
  const float* outb = (const float*)d_in[18];
  const float* propW = (const float*)d_in[19];
  const float* propb = (const float*)d_in[20];
  float* out = (float*)d_out;   // fp32: [B*16 preds][B*S propensity]

  // ---- workspace layout: fp32 section then bf16 section (~52.4 MB) ----
  float* ws = (float*)d_ws;
  float* ed    = ws;                           // B*128
  float* gd_e  = ed    + (size_t)B*128;        // B*G
  float* gd_d  = gd_e  + (size_t)B*G;          // B*G
  float* cb    = gd_d  + (size_t)B*G;          // B*H
  float* encWe = cb    + (size_t)B*H;          // B*S
  float* nub   = encWe + (size_t)B*S;          // B*S
  float* yb    = nub   + (size_t)B*S;          // B
  float* dh32  = yb    + B;                    // B*H
  __hip_bfloat16* bf = (__hip_bfloat16*)(dh32 + (size_t)B*H);
  __hip_bfloat16* ex16 = bf;                              // B*S*128
  __hip_bfloat16* eo16 = ex16 + (size_t)B*S*128;          // B*S*H
  __hip_bfloat16* h16A = eo16 + (size_t)B*S*H;            // B*H (enc t=0 zeros; dec ping)
  __hip_bfloat16* h16B = h16A + (size_t)B*H;              // B*H (dec pong)
  __hip_bfloat16* W16E = h16B + (size_t)B*H;              // 2048*640
  __hip_bfloat16* W16D = W16E + (size_t)G*640;            // 2048*512

  init_kernel<<<(B*H + 255)/256, 256, 0, stream>>>(cb, (unsigned*)h16A, yb, fio);
  embed_x2<<<256, 256, 0, stream>>>(temporal_x, temp_W, temp_b, ex16);
  embed_d_kernel<<<B, 128, 0, stream>>>(static_x, stat_W, stat_b, ed);
  gd_kernel<<<dim3(B,8), 256, 0, stream>>>(ed, eWih, 128, eb, gd_e);
  gd_kernel<<<dim3(B,8), 256, 0, stream>>>(ed, dWih, 0, dbias, gd_d);
  wtrans_kernel<<<dim3(10,32), 256, 0, stream>>>(eWih, 128, eWhh, W16E, 640);
  wtrans_kernel<<<dim3(8,32),  256, 0, stream>>>(dWhh, 0,   dWhh, W16D, 512);

  const float* wr256p = eWih + (size_t)256*G;

  // encoder: h(t) lives in eo16[:,t,:]; t=0 reads zeroed h16A.
  for (int t = 0; t < S; ++t){
    const __hip_bfloat16* hin = (t == 0) ? h16A : (eo16 + (size_t)(t-1)*H);
    const int hs = (t == 0) ? H : S*H;
    enc_step5<<<256, 256, 0, stream>>>(ex16, hin, hs, W16E, gd_e, wr256p,
                                       hist, cb, eo16, t);
  }

  prop_we_kernel<<<(B*S)/4, 256, 0, stream>>>(eo16, propW, propb, attnW, outW + 512,
                                              out + B*16, encWe, nub);

  // decoder: t=0 reads h_n = eo16[:,S-1,:]; then ping-pong h16B/h16A.
  for (int t = 0; t < 16; ++t){
    const __hip_bfloat16* hin; int hs;
    if (t == 0){ hin = eo16 + (size_t)(S-1)*H; hs = S*H; }
    else { hin = (t & 1) ? h16B : h16A; hs = H; }
    __hip_bfloat16* hout16 = (t & 1) ? h16A : h16B;
    dec_step5<<<256, 256, 0, stream>>>(hin, hs, W16D, gd_d,
                                       dWih + (size_t)128*G, dWih + (size_t)129*G,
                                       yb, fut, cb, dh32, hout16, t);
    attn_pred3<<<B, 512, 0, stream>>>(eo16, encWe, nub, dh32, attnW, attnb, outW, outb,
                                      fut, yb, out, t);
  }
}